// Round 1
// baseline (5710.321 us; speedup 1.0000x reference)
//
#include <hip/hip_runtime.h>
#include <math.h>

// ---------------------------------------------------------------------------
// HGT layer slice, fp32 reference-faithful implementation.
//
// Pipeline (all on `stream`, graph-capture safe):
//   1. init        : zero agg/segsum/counters, segmax=-inf, lists=-1
//   2. hist        : per-type node counts, per-relation edge counts
//   3. offsets     : serial 8-entry padded exclusive scan (1 thread)
//   4. scatter     : bucket node ids by type, edge ids by relation (chunks of
//                    32, padded with -1 so every 32-chunk is type-uniform)
//   5. kqv         : per type-uniform 32-node tile: h[32,128] @ {Wk,Wq,Wv}[t]
//   6. score       : per relation-uniform 32-edge tile: gather k[src] rows,
//                    GEMM with att[r], dot with q[dst], segmax atomicMax
//   7. expsum      : ex = exp(s - m), segsum atomicAdd
//   8. agg         : gather v[src] rows, GEMM with msg[r], scale by alpha,
//                    atomicAdd into agg[dst]
//   9. out         : per type-uniform 32-node tile: agg @ a_w[t] * sigmoid(skip)
//
// ws layout (fp32 indices): k,q,v,agg [N*128 each], escore [E],
// segmax/segsum [N*R each], then int region (node_list, edge_list, counters).
// Total ~105 MB.
// ---------------------------------------------------------------------------

#define N_NODES 50000
#define N_EDGES 500000
#define DIM 128
#define TT 8
#define RR 8
#define SEGS (N_NODES * RR)
#define CH 32
#define RSQRT_DK 0.08838834764831845f

// grids for the bucketed tile kernels (cover padded totals)
#define KQV_GRID 1571               // 1571*32 = 50272 >= 50000 + 8*31
#define EDGE_GRID 15633             // 15633*32 = 500256 >= 500000 + 8*31
#define NODE_LIST_LEN (KQV_GRID * CH)
#define EDGE_LIST_LEN (EDGE_GRID * CH)
#define GRID_E ((N_EDGES + 255) / 256)   // 1954, also covers N

// float-index offsets into ws
#define OFF_K 0
#define OFF_Q 6400000
#define OFF_V 12800000
#define OFF_AGG 19200000
#define OFF_ESC 25600000
#define OFF_SMAX 26100000
#define OFF_SSUM 26500000
#define OFF_INT 26900000            // int region starts here (same 4B units)
// int offsets relative to (int*)ws + OFF_INT
#define IO_NLIST 0
#define IO_ELIST NODE_LIST_LEN                 // 50272
#define IO_CNT_N (IO_ELIST + EDGE_LIST_LEN)    // 550528
#define IO_CUR_N (IO_CNT_N + 8)
#define IO_POFF_N (IO_CUR_N + 8)
#define IO_CNT_E (IO_POFF_N + 16)
#define IO_CUR_E (IO_CNT_E + 8)
#define IO_POFF_E (IO_CUR_E + 8)

__device__ inline void atomicMaxFloat(float* addr, float val) {
    // sign-split trick: float ordering == int ordering for >=0,
    // == reversed-unsigned ordering for <0. Init value is -inf.
    if (val >= 0.f)
        atomicMax((int*)addr, __float_as_int(val));
    else
        atomicMin((unsigned int*)addr, (unsigned int)__float_as_int(val));
}

__global__ void init_kernel(float* wsf, int* wsi) {
    int i = blockIdx.x * blockDim.x + threadIdx.x;
    if (i < N_NODES * DIM) wsf[OFF_AGG + i] = 0.f;
    if (i < SEGS) {
        wsf[OFF_SMAX + i] = __int_as_float((int)0xFF800000u);  // -inf
        wsf[OFF_SSUM + i] = 0.f;
    }
    if (i < NODE_LIST_LEN) wsi[IO_NLIST + i] = -1;
    if (i < EDGE_LIST_LEN) wsi[IO_ELIST + i] = -1;
    if (i < 64) wsi[IO_CNT_N + i] = 0;  // counts, cursors, offsets region
}

__global__ void hist_kernel(const int* __restrict__ ntype,
                            const int* __restrict__ etype, int* wsi) {
    int i = blockIdx.x * blockDim.x + threadIdx.x;
    if (i < N_NODES) atomicAdd(&wsi[IO_CNT_N + ntype[i]], 1);
    if (i < N_EDGES) atomicAdd(&wsi[IO_CNT_E + etype[i]], 1);
}

__global__ void offsets_kernel(int* wsi) {
    // single thread: 8-entry padded exclusive scans
    int off = 0;
    for (int t = 0; t < TT; ++t) {
        wsi[IO_POFF_N + t] = off;
        off += ((wsi[IO_CNT_N + t] + CH - 1) / CH) * CH;
    }
    wsi[IO_POFF_N + TT] = off;
    off = 0;
    for (int r = 0; r < RR; ++r) {
        wsi[IO_POFF_E + r] = off;
        off += ((wsi[IO_CNT_E + r] + CH - 1) / CH) * CH;
    }
    wsi[IO_POFF_E + RR] = off;
}

__global__ void scatter_kernel(const int* __restrict__ ntype,
                               const int* __restrict__ etype, int* wsi) {
    int i = blockIdx.x * blockDim.x + threadIdx.x;
    if (i < N_NODES) {
        int t = ntype[i];
        int pos = wsi[IO_POFF_N + t] + atomicAdd(&wsi[IO_CUR_N + t], 1);
        wsi[IO_NLIST + pos] = i;
    }
    if (i < N_EDGES) {
        int r = etype[i];
        int pos = wsi[IO_POFF_E + r] + atomicAdd(&wsi[IO_CUR_E + r], 1);
        wsi[IO_ELIST + pos] = i;
    }
}

// --- tile GEMM kernels: 256 threads, 32 rows x 128 cols, K=128 -------------
// thread (te,tc): te=tid/32 in [0,8) -> 4 rows, tc=tid%32 -> 4 cols (float4)
// LDS row stride 132: inner-loop reads hl[row][i] land in 2 distinct banks
// per wave (broadcast within each) -> conflict-free.

__global__ __launch_bounds__(256) void kqv_kernel(
    const float* __restrict__ h, const int* __restrict__ ntype,
    const float* __restrict__ Wk, const float* __restrict__ Wq,
    const float* __restrict__ Wv, const int* __restrict__ nlist,
    float* __restrict__ kout, float* __restrict__ qout,
    float* __restrict__ vout) {
    __shared__ float hl[CH][DIM + 4];
    __shared__ int nid[CH];
    int tid = threadIdx.x;
    int base = blockIdx.x * CH;
    if (tid < CH) nid[tid] = nlist[base + tid];
    __syncthreads();
    int first = -1;
#pragma unroll
    for (int j = 0; j < CH; ++j)
        if (first < 0 && nid[j] >= 0) first = nid[j];
    if (first < 0) return;  // block-uniform: chunk entirely padding
    int t = ntype[first];

    for (int r2 = 0; r2 < CH; r2 += 2) {
        int row = r2 + (tid >> 7);
        int col = tid & 127;
        int n = nid[row];
        if (n < 0) n = 0;
        hl[row][col] = h[(size_t)n * DIM + col];
    }
    __syncthreads();
    int te = tid >> 5, tc = tid & 31;

#pragma unroll
    for (int w = 0; w < 3; ++w) {
        const float* W = (w == 0 ? Wk : (w == 1 ? Wq : Wv)) + (size_t)t * DIM * DIM;
        const float4* W4 = (const float4*)W;
        float* O = (w == 0 ? kout : (w == 1 ? qout : vout));
        float acc[4][4] = {};
        for (int i = 0; i < DIM; ++i) {
            float4 a = W4[i * 32 + tc];
#pragma unroll
            for (int j = 0; j < 4; ++j) {
                float hv = hl[te * 4 + j][i];
                acc[j][0] += hv * a.x;
                acc[j][1] += hv * a.y;
                acc[j][2] += hv * a.z;
                acc[j][3] += hv * a.w;
            }
        }
#pragma unroll
        for (int j = 0; j < 4; ++j) {
            int n = nid[te * 4 + j];
            if (n >= 0) {
                float4 o = make_float4(acc[j][0], acc[j][1], acc[j][2], acc[j][3]);
                ((float4*)(O + (size_t)n * DIM))[tc] = o;
            }
        }
    }
}

__global__ __launch_bounds__(256) void score_kernel(
    const float* __restrict__ kbuf, const float* __restrict__ qbuf,
    const float* __restrict__ att, const float* __restrict__ pri,
    const int* __restrict__ adj, const int* __restrict__ etype,
    const int* __restrict__ elist, float* __restrict__ esc,
    float* __restrict__ smax) {
    __shared__ float kl[CH][DIM + 4];
    __shared__ int eid[CH], es[CH], ed[CH];
    int tid = threadIdx.x;
    int base = blockIdx.x * CH;
    if (tid < CH) {
        int e = elist[base + tid];
        eid[tid] = e;
        es[tid] = (e >= 0) ? adj[e] : 0;
        ed[tid] = (e >= 0) ? adj[N_EDGES + e] : 0;
    }
    __syncthreads();
    int firste = -1;
#pragma unroll
    for (int j = 0; j < CH; ++j)
        if (firste < 0 && eid[j] >= 0) firste = eid[j];
    if (firste < 0) return;
    int rel = etype[firste];

    for (int r2 = 0; r2 < CH; r2 += 2) {
        int row = r2 + (tid >> 7);
        int col = tid & 127;
        kl[row][col] = kbuf[(size_t)es[row] * DIM + col];
    }
    __syncthreads();
    int te = tid >> 5, tc = tid & 31;
    const float4* A4 = (const float4*)(att + (size_t)rel * DIM * DIM);
    float acc[4][4] = {};
    for (int i = 0; i < DIM; ++i) {
        float4 a = A4[i * 32 + tc];
#pragma unroll
        for (int j = 0; j < 4; ++j) {
            float kv = kl[te * 4 + j][i];
            acc[j][0] += kv * a.x;
            acc[j][1] += kv * a.y;
            acc[j][2] += kv * a.z;
            acc[j][3] += kv * a.w;
        }
    }
    float prv = pri[rel] * RSQRT_DK;
#pragma unroll
    for (int j = 0; j < 4; ++j) {
        int erow = te * 4 + j;
        int dstn = ed[erow];
        float4 qv = ((const float4*)(qbuf + (size_t)dstn * DIM))[tc];
        float p = acc[j][0] * qv.x + acc[j][1] * qv.y + acc[j][2] * qv.z +
                  acc[j][3] * qv.w;
        p += __shfl_down(p, 16, 32);
        p += __shfl_down(p, 8, 32);
        p += __shfl_down(p, 4, 32);
        p += __shfl_down(p, 2, 32);
        p += __shfl_down(p, 1, 32);
        if (tc == 0) {
            int e = eid[erow];
            if (e >= 0) {
                float s = p * prv;
                esc[e] = s;
                atomicMaxFloat(&smax[(size_t)dstn * RR + rel], s);
            }
        }
    }
}

__global__ void expsum_kernel(const int* __restrict__ adj,
                              const int* __restrict__ etype,
                              float* __restrict__ esc,
                              const float* __restrict__ smax,
                              float* __restrict__ ssum) {
    int e = blockIdx.x * blockDim.x + threadIdx.x;
    if (e < N_EDGES) {
        int dstn = adj[N_EDGES + e];
        int seg = dstn * RR + etype[e];
        float ex = __expf(esc[e] - smax[seg]);
        esc[e] = ex;
        atomicAdd(&ssum[seg], ex);
    }
}

__global__ __launch_bounds__(256) void agg_kernel(
    const float* __restrict__ vbuf, const float* __restrict__ msg,
    const int* __restrict__ adj, const int* __restrict__ etype,
    const int* __restrict__ elist, const float* __restrict__ esc,
    const float* __restrict__ ssum, float* __restrict__ agg) {
    __shared__ float vl[CH][DIM + 4];
    __shared__ int eid[CH], es[CH], ed[CH];
    int tid = threadIdx.x;
    int base = blockIdx.x * CH;
    if (tid < CH) {
        int e = elist[base + tid];
        eid[tid] = e;
        es[tid] = (e >= 0) ? adj[e] : 0;
        ed[tid] = (e >= 0) ? adj[N_EDGES + e] : 0;
    }
    __syncthreads();
    int firste = -1;
#pragma unroll
    for (int j = 0; j < CH; ++j)
        if (firste < 0 && eid[j] >= 0) firste = eid[j];
    if (firste < 0) return;
    int rel = etype[firste];

    for (int r2 = 0; r2 < CH; r2 += 2) {
        int row = r2 + (tid >> 7);
        int col = tid & 127;
        vl[row][col] = vbuf[(size_t)es[row] * DIM + col];
    }
    __syncthreads();
    int te = tid >> 5, tc = tid & 31;
    const float4* M4 = (const float4*)(msg + (size_t)rel * DIM * DIM);
    float acc[4][4] = {};
    for (int i = 0; i < DIM; ++i) {
        float4 a = M4[i * 32 + tc];
#pragma unroll
        for (int j = 0; j < 4; ++j) {
            float vv = vl[te * 4 + j][i];
            acc[j][0] += vv * a.x;
            acc[j][1] += vv * a.y;
            acc[j][2] += vv * a.z;
            acc[j][3] += vv * a.w;
        }
    }
#pragma unroll
    for (int j = 0; j < 4; ++j) {
        int erow = te * 4 + j;
        int e = eid[erow];
        if (e >= 0) {
            int dstn = ed[erow];
            float alpha = esc[e] / ssum[(size_t)dstn * RR + rel];
            float* p = agg + (size_t)dstn * DIM + tc * 4;
            atomicAdd(p + 0, acc[j][0] * alpha);
            atomicAdd(p + 1, acc[j][1] * alpha);
            atomicAdd(p + 2, acc[j][2] * alpha);
            atomicAdd(p + 3, acc[j][3] * alpha);
        }
    }
}

__global__ __launch_bounds__(256) void out_kernel(
    const float* __restrict__ agg, const int* __restrict__ ntype,
    const float* __restrict__ Wa, const float* __restrict__ skip,
    const int* __restrict__ nlist, float* __restrict__ out) {
    __shared__ float gl[CH][DIM + 4];
    __shared__ int nid[CH];
    int tid = threadIdx.x;
    int base = blockIdx.x * CH;
    if (tid < CH) nid[tid] = nlist[base + tid];
    __syncthreads();
    int first = -1;
#pragma unroll
    for (int j = 0; j < CH; ++j)
        if (first < 0 && nid[j] >= 0) first = nid[j];
    if (first < 0) return;
    int t = ntype[first];
    float sig = 1.f / (1.f + __expf(-skip[t]));

    for (int r2 = 0; r2 < CH; r2 += 2) {
        int row = r2 + (tid >> 7);
        int col = tid & 127;
        int n = nid[row];
        if (n < 0) n = 0;
        gl[row][col] = agg[(size_t)n * DIM + col];
    }
    __syncthreads();
    int te = tid >> 5, tc = tid & 31;
    const float4* W4 = (const float4*)(Wa + (size_t)t * DIM * DIM);
    float acc[4][4] = {};
    for (int i = 0; i < DIM; ++i) {
        float4 a = W4[i * 32 + tc];
#pragma unroll
        for (int j = 0; j < 4; ++j) {
            float gv = gl[te * 4 + j][i];
            acc[j][0] += gv * a.x;
            acc[j][1] += gv * a.y;
            acc[j][2] += gv * a.z;
            acc[j][3] += gv * a.w;
        }
    }
#pragma unroll
    for (int j = 0; j < 4; ++j) {
        int n = nid[te * 4 + j];
        if (n >= 0) {
            float4 o = make_float4(acc[j][0] * sig, acc[j][1] * sig,
                                   acc[j][2] * sig, acc[j][3] * sig);
            ((float4*)(out + (size_t)n * DIM))[tc] = o;
        }
    }
}

extern "C" void kernel_launch(void* const* d_in, const int* in_sizes, int n_in,
                              void* d_out, int out_size, void* d_ws,
                              size_t ws_size, hipStream_t stream) {
    const float* h = (const float*)d_in[0];
    const int* adj = (const int*)d_in[1];
    const int* etype = (const int*)d_in[2];
    const int* ntype = (const int*)d_in[3];
    // d_in[4] src_type, d_in[5] dst_type: unused by the reference math
    const float* Wk = (const float*)d_in[6];
    const float* Wq = (const float*)d_in[7];
    const float* Wv = (const float*)d_in[8];
    const float* Wa = (const float*)d_in[9];
    const float* pri = (const float*)d_in[10];
    const float* att = (const float*)d_in[11];
    const float* msg = (const float*)d_in[12];
    const float* skip = (const float*)d_in[13];
    float* out = (float*)d_out;

    float* wsf = (float*)d_ws;
    int* wsi = (int*)d_ws + OFF_INT;
    float* kb = wsf + OFF_K;
    float* qb = wsf + OFF_Q;
    float* vb = wsf + OFF_V;
    float* ab = wsf + OFF_AGG;
    float* esc = wsf + OFF_ESC;
    float* smax = wsf + OFF_SMAX;
    float* ssum = wsf + OFF_SSUM;

    init_kernel<<<(N_NODES * DIM + 255) / 256, 256, 0, stream>>>(wsf, wsi);
    hist_kernel<<<GRID_E, 256, 0, stream>>>(ntype, etype, wsi);
    offsets_kernel<<<1, 1, 0, stream>>>(wsi);
    scatter_kernel<<<GRID_E, 256, 0, stream>>>(ntype, etype, wsi);
    kqv_kernel<<<KQV_GRID, 256, 0, stream>>>(h, ntype, Wk, Wq, Wv,
                                             wsi + IO_NLIST, kb, qb, vb);
    score_kernel<<<EDGE_GRID, 256, 0, stream>>>(kb, qb, att, pri, adj, etype,
                                                wsi + IO_ELIST, esc, smax);
    expsum_kernel<<<GRID_E, 256, 0, stream>>>(adj, etype, esc, smax, ssum);
    agg_kernel<<<EDGE_GRID, 256, 0, stream>>>(vb, msg, adj, etype,
                                              wsi + IO_ELIST, esc, ssum, ab);
    out_kernel<<<KQV_GRID, 256, 0, stream>>>(ab, ntype, Wa, skip,
                                             wsi + IO_NLIST, out);
}

// Round 2
// 1493.948 us; speedup vs baseline: 3.8223x; 3.8223x over previous
//
#include <hip/hip_runtime.h>
#include <math.h>

// ---------------------------------------------------------------------------
// HGT layer slice, fp32 reference-faithful implementation.
//
// Pipeline (all on `stream`, graph-capture safe):
//   1. init        : zero agg/segsum/counters, segmax=-inf, lists=-1
//   2. hist        : per-type node counts, per-relation edge counts
//                    (LDS-aggregated: 8 global atomics per block, not 256)
//   3. offsets     : serial 8-entry padded exclusive scan (1 thread)
//   4. scatter     : bucket node ids by type, edge ids by relation.
//                    LDS-rank + one block-level global reservation per type
//                    (R1 post-mortem: per-thread global atomics on 8 words
//                    serialized -> 2.4 ms; this drops it ~100x)
//   5. kqv         : per type-uniform 32-node tile: h[32,128] @ {Wk,Wq,Wv}[t]
//   6. score       : per relation-uniform 32-edge tile: gather k[src] rows,
//                    GEMM with att[r], dot with q[dst], segmax atomicMax
//   7. expsum      : ex = exp(s - m), segsum atomicAdd
//   8. agg         : gather v[src] rows, GEMM with msg[r], scale by alpha,
//                    atomicAdd into agg[dst]
//   9. out         : per type-uniform 32-node tile: agg @ a_w[t] * sigmoid(skip)
// ---------------------------------------------------------------------------

#define N_NODES 50000
#define N_EDGES 500000
#define DIM 128
#define TT 8
#define RR 8
#define SEGS (N_NODES * RR)
#define CH 32
#define RSQRT_DK 0.08838834764831845f

// grids for the bucketed tile kernels (cover padded totals)
#define KQV_GRID 1571               // 1571*32 = 50272 >= 50000 + 8*31
#define EDGE_GRID 15633             // 15633*32 = 500256 >= 500000 + 8*31
#define NODE_LIST_LEN (KQV_GRID * CH)
#define EDGE_LIST_LEN (EDGE_GRID * CH)
#define GRID_E ((N_EDGES + 255) / 256)   // 1954, also covers N

// float-index offsets into ws
#define OFF_K 0
#define OFF_Q 6400000
#define OFF_V 12800000
#define OFF_AGG 19200000
#define OFF_ESC 25600000
#define OFF_SMAX 26100000
#define OFF_SSUM 26500000
#define OFF_INT 26900000            // int region starts here (same 4B units)
// int offsets relative to (int*)ws + OFF_INT
#define IO_NLIST 0
#define IO_ELIST NODE_LIST_LEN                 // 50272
#define IO_CNT_N (IO_ELIST + EDGE_LIST_LEN)    // 550528
#define IO_CUR_N (IO_CNT_N + 8)
#define IO_POFF_N (IO_CUR_N + 8)
#define IO_CNT_E (IO_POFF_N + 16)
#define IO_CUR_E (IO_CNT_E + 8)
#define IO_POFF_E (IO_CUR_E + 8)

__device__ inline void atomicMaxFloat(float* addr, float val) {
    // sign-split trick: float ordering == int ordering for >=0,
    // == reversed-unsigned ordering for <0. Init value is -inf.
    if (val >= 0.f)
        atomicMax((int*)addr, __float_as_int(val));
    else
        atomicMin((unsigned int*)addr, (unsigned int)__float_as_int(val));
}

__global__ void init_kernel(float* wsf, int* wsi) {
    int i = blockIdx.x * blockDim.x + threadIdx.x;
    if (i < N_NODES * DIM) wsf[OFF_AGG + i] = 0.f;
    if (i < SEGS) {
        wsf[OFF_SMAX + i] = __int_as_float((int)0xFF800000u);  // -inf
        wsf[OFF_SSUM + i] = 0.f;
    }
    if (i < NODE_LIST_LEN) wsi[IO_NLIST + i] = -1;
    if (i < EDGE_LIST_LEN) wsi[IO_ELIST + i] = -1;
    if (i < 64) wsi[IO_CNT_N + i] = 0;  // counts, cursors, offsets region
}

// LDS-aggregated histogram: 256 per-thread LDS atomics -> <=16 global atomics
__global__ void hist_kernel(const int* __restrict__ ntype,
                            const int* __restrict__ etype, int* wsi) {
    __shared__ int cn[TT], ce[RR];
    int tid = threadIdx.x;
    if (tid < TT) cn[tid] = 0;
    if (tid >= TT && tid < TT + RR) ce[tid - TT] = 0;
    __syncthreads();
    int i = blockIdx.x * blockDim.x + tid;
    if (i < N_NODES) atomicAdd(&cn[ntype[i]], 1);
    if (i < N_EDGES) atomicAdd(&ce[etype[i]], 1);
    __syncthreads();
    if (tid < TT && cn[tid] > 0) atomicAdd(&wsi[IO_CNT_N + tid], cn[tid]);
    if (tid >= TT && tid < TT + RR && ce[tid - TT] > 0)
        atomicAdd(&wsi[IO_CNT_E + tid - TT], ce[tid - TT]);
}

__global__ void offsets_kernel(int* wsi) {
    // single thread: 8-entry padded exclusive scans
    int off = 0;
    for (int t = 0; t < TT; ++t) {
        wsi[IO_POFF_N + t] = off;
        off += ((wsi[IO_CNT_N + t] + CH - 1) / CH) * CH;
    }
    wsi[IO_POFF_N + TT] = off;
    off = 0;
    for (int r = 0; r < RR; ++r) {
        wsi[IO_POFF_E + r] = off;
        off += ((wsi[IO_CNT_E + r] + CH - 1) / CH) * CH;
    }
    wsi[IO_POFF_E + RR] = off;
}

// LDS local rank + one global range reservation per (block, type):
// global atomic count drops from 550k to ~16k spread over 16 words.
__global__ void scatter_kernel(const int* __restrict__ ntype,
                               const int* __restrict__ etype, int* wsi) {
    __shared__ int cn[TT], ce[RR], bn[TT], be[RR];
    int tid = threadIdx.x;
    if (tid < TT) cn[tid] = 0;
    if (tid >= TT && tid < TT + RR) ce[tid - TT] = 0;
    __syncthreads();
    int i = blockIdx.x * blockDim.x + tid;
    int t = -1, rnk_n = 0, r = -1, rnk_e = 0;
    if (i < N_NODES) {
        t = ntype[i];
        rnk_n = atomicAdd(&cn[t], 1);
    }
    if (i < N_EDGES) {
        r = etype[i];
        rnk_e = atomicAdd(&ce[r], 1);
    }
    __syncthreads();
    if (tid < TT && cn[tid] > 0) bn[tid] = atomicAdd(&wsi[IO_CUR_N + tid], cn[tid]);
    if (tid >= TT && tid < TT + RR && ce[tid - TT] > 0)
        be[tid - TT] = atomicAdd(&wsi[IO_CUR_E + tid - TT], ce[tid - TT]);
    __syncthreads();
    if (t >= 0)
        wsi[IO_NLIST + wsi[IO_POFF_N + t] + bn[t] + rnk_n] = i;
    if (r >= 0)
        wsi[IO_ELIST + wsi[IO_POFF_E + r] + be[r] + rnk_e] = i;
}

// --- tile GEMM kernels: 256 threads, 32 rows x 128 cols, K=128 -------------
// thread (te,tc): te=tid/32 in [0,8) -> 4 rows, tc=tid%32 -> 4 cols (float4)
// LDS row stride 132: inner-loop reads hl[row][i] land in 2 distinct banks
// per wave (broadcast within each) -> conflict-free.

__global__ __launch_bounds__(256) void kqv_kernel(
    const float* __restrict__ h, const int* __restrict__ ntype,
    const float* __restrict__ Wk, const float* __restrict__ Wq,
    const float* __restrict__ Wv, const int* __restrict__ nlist,
    float* __restrict__ kout, float* __restrict__ qout,
    float* __restrict__ vout) {
    __shared__ float hl[CH][DIM + 4];
    __shared__ int nid[CH];
    int tid = threadIdx.x;
    int base = blockIdx.x * CH;
    if (tid < CH) nid[tid] = nlist[base + tid];
    __syncthreads();
    int first = -1;
#pragma unroll
    for (int j = 0; j < CH; ++j)
        if (first < 0 && nid[j] >= 0) first = nid[j];
    if (first < 0) return;  // block-uniform: chunk entirely padding
    int t = ntype[first];

    for (int r2 = 0; r2 < CH; r2 += 2) {
        int row = r2 + (tid >> 7);
        int col = tid & 127;
        int n = nid[row];
        if (n < 0) n = 0;
        hl[row][col] = h[(size_t)n * DIM + col];
    }
    __syncthreads();
    int te = tid >> 5, tc = tid & 31;

#pragma unroll
    for (int w = 0; w < 3; ++w) {
        const float* W = (w == 0 ? Wk : (w == 1 ? Wq : Wv)) + (size_t)t * DIM * DIM;
        const float4* W4 = (const float4*)W;
        float* O = (w == 0 ? kout : (w == 1 ? qout : vout));
        float acc[4][4] = {};
        for (int i = 0; i < DIM; ++i) {
            float4 a = W4[i * 32 + tc];
#pragma unroll
            for (int j = 0; j < 4; ++j) {
                float hv = hl[te * 4 + j][i];
                acc[j][0] += hv * a.x;
                acc[j][1] += hv * a.y;
                acc[j][2] += hv * a.z;
                acc[j][3] += hv * a.w;
            }
        }
#pragma unroll
        for (int j = 0; j < 4; ++j) {
            int n = nid[te * 4 + j];
            if (n >= 0) {
                float4 o = make_float4(acc[j][0], acc[j][1], acc[j][2], acc[j][3]);
                ((float4*)(O + (size_t)n * DIM))[tc] = o;
            }
        }
    }
}

__global__ __launch_bounds__(256) void score_kernel(
    const float* __restrict__ kbuf, const float* __restrict__ qbuf,
    const float* __restrict__ att, const float* __restrict__ pri,
    const int* __restrict__ adj, const int* __restrict__ etype,
    const int* __restrict__ elist, float* __restrict__ esc,
    float* __restrict__ smax) {
    __shared__ float kl[CH][DIM + 4];
    __shared__ int eid[CH], es[CH], ed[CH];
    int tid = threadIdx.x;
    int base = blockIdx.x * CH;
    if (tid < CH) {
        int e = elist[base + tid];
        eid[tid] = e;
        es[tid] = (e >= 0) ? adj[e] : 0;
        ed[tid] = (e >= 0) ? adj[N_EDGES + e] : 0;
    }
    __syncthreads();
    int firste = -1;
#pragma unroll
    for (int j = 0; j < CH; ++j)
        if (firste < 0 && eid[j] >= 0) firste = eid[j];
    if (firste < 0) return;
    int rel = etype[firste];

    for (int r2 = 0; r2 < CH; r2 += 2) {
        int row = r2 + (tid >> 7);
        int col = tid & 127;
        kl[row][col] = kbuf[(size_t)es[row] * DIM + col];
    }
    __syncthreads();
    int te = tid >> 5, tc = tid & 31;
    const float4* A4 = (const float4*)(att + (size_t)rel * DIM * DIM);
    float acc[4][4] = {};
    for (int i = 0; i < DIM; ++i) {
        float4 a = A4[i * 32 + tc];
#pragma unroll
        for (int j = 0; j < 4; ++j) {
            float kv = kl[te * 4 + j][i];
            acc[j][0] += kv * a.x;
            acc[j][1] += kv * a.y;
            acc[j][2] += kv * a.z;
            acc[j][3] += kv * a.w;
        }
    }
    float prv = pri[rel] * RSQRT_DK;
#pragma unroll
    for (int j = 0; j < 4; ++j) {
        int erow = te * 4 + j;
        int dstn = ed[erow];
        float4 qv = ((const float4*)(qbuf + (size_t)dstn * DIM))[tc];
        float p = acc[j][0] * qv.x + acc[j][1] * qv.y + acc[j][2] * qv.z +
                  acc[j][3] * qv.w;
        p += __shfl_down(p, 16, 32);
        p += __shfl_down(p, 8, 32);
        p += __shfl_down(p, 4, 32);
        p += __shfl_down(p, 2, 32);
        p += __shfl_down(p, 1, 32);
        if (tc == 0) {
            int e = eid[erow];
            if (e >= 0) {
                float s = p * prv;
                esc[e] = s;
                atomicMaxFloat(&smax[(size_t)dstn * RR + rel], s);
            }
        }
    }
}

__global__ void expsum_kernel(const int* __restrict__ adj,
                              const int* __restrict__ etype,
                              float* __restrict__ esc,
                              const float* __restrict__ smax,
                              float* __restrict__ ssum) {
    int e = blockIdx.x * blockDim.x + threadIdx.x;
    if (e < N_EDGES) {
        int dstn = adj[N_EDGES + e];
        int seg = dstn * RR + etype[e];
        float ex = __expf(esc[e] - smax[seg]);
        esc[e] = ex;
        atomicAdd(&ssum[seg], ex);
    }
}

__global__ __launch_bounds__(256) void agg_kernel(
    const float* __restrict__ vbuf, const float* __restrict__ msg,
    const int* __restrict__ adj, const int* __restrict__ etype,
    const int* __restrict__ elist, const float* __restrict__ esc,
    const float* __restrict__ ssum, float* __restrict__ agg) {
    __shared__ float vl[CH][DIM + 4];
    __shared__ int eid[CH], es[CH], ed[CH];
    int tid = threadIdx.x;
    int base = blockIdx.x * CH;
    if (tid < CH) {
        int e = elist[base + tid];
        eid[tid] = e;
        es[tid] = (e >= 0) ? adj[e] : 0;
        ed[tid] = (e >= 0) ? adj[N_EDGES + e] : 0;
    }
    __syncthreads();
    int firste = -1;
#pragma unroll
    for (int j = 0; j < CH; ++j)
        if (firste < 0 && eid[j] >= 0) firste = eid[j];
    if (firste < 0) return;
    int rel = etype[firste];

    for (int r2 = 0; r2 < CH; r2 += 2) {
        int row = r2 + (tid >> 7);
        int col = tid & 127;
        vl[row][col] = vbuf[(size_t)es[row] * DIM + col];
    }
    __syncthreads();
    int te = tid >> 5, tc = tid & 31;
    const float4* M4 = (const float4*)(msg + (size_t)rel * DIM * DIM);
    float acc[4][4] = {};
    for (int i = 0; i < DIM; ++i) {
        float4 a = M4[i * 32 + tc];
#pragma unroll
        for (int j = 0; j < 4; ++j) {
            float vv = vl[te * 4 + j][i];
            acc[j][0] += vv * a.x;
            acc[j][1] += vv * a.y;
            acc[j][2] += vv * a.z;
            acc[j][3] += vv * a.w;
        }
    }
#pragma unroll
    for (int j = 0; j < 4; ++j) {
        int erow = te * 4 + j;
        int e = eid[erow];
        if (e >= 0) {
            int dstn = ed[erow];
            float alpha = esc[e] / ssum[(size_t)dstn * RR + rel];
            float* p = agg + (size_t)dstn * DIM + tc * 4;
            atomicAdd(p + 0, acc[j][0] * alpha);
            atomicAdd(p + 1, acc[j][1] * alpha);
            atomicAdd(p + 2, acc[j][2] * alpha);
            atomicAdd(p + 3, acc[j][3] * alpha);
        }
    }
}

__global__ __launch_bounds__(256) void out_kernel(
    const float* __restrict__ agg, const int* __restrict__ ntype,
    const float* __restrict__ Wa, const float* __restrict__ skip,
    const int* __restrict__ nlist, float* __restrict__ out) {
    __shared__ float gl[CH][DIM + 4];
    __shared__ int nid[CH];
    int tid = threadIdx.x;
    int base = blockIdx.x * CH;
    if (tid < CH) nid[tid] = nlist[base + tid];
    __syncthreads();
    int first = -1;
#pragma unroll
    for (int j = 0; j < CH; ++j)
        if (first < 0 && nid[j] >= 0) first = nid[j];
    if (first < 0) return;
    int t = ntype[first];
    float sig = 1.f / (1.f + __expf(-skip[t]));

    for (int r2 = 0; r2 < CH; r2 += 2) {
        int row = r2 + (tid >> 7);
        int col = tid & 127;
        int n = nid[row];
        if (n < 0) n = 0;
        gl[row][col] = agg[(size_t)n * DIM + col];
    }
    __syncthreads();
    int te = tid >> 5, tc = tid & 31;
    const float4* W4 = (const float4*)(Wa + (size_t)t * DIM * DIM);
    float acc[4][4] = {};
    for (int i = 0; i < DIM; ++i) {
        float4 a = W4[i * 32 + tc];
#pragma unroll
        for (int j = 0; j < 4; ++j) {
            float gv = gl[te * 4 + j][i];
            acc[j][0] += gv * a.x;
            acc[j][1] += gv * a.y;
            acc[j][2] += gv * a.z;
            acc[j][3] += gv * a.w;
        }
    }
#pragma unroll
    for (int j = 0; j < 4; ++j) {
        int n = nid[te * 4 + j];
        if (n >= 0) {
            float4 o = make_float4(acc[j][0] * sig, acc[j][1] * sig,
                                   acc[j][2] * sig, acc[j][3] * sig);
            ((float4*)(out + (size_t)n * DIM))[tc] = o;
        }
    }
}

extern "C" void kernel_launch(void* const* d_in, const int* in_sizes, int n_in,
                              void* d_out, int out_size, void* d_ws,
                              size_t ws_size, hipStream_t stream) {
    const float* h = (const float*)d_in[0];
    const int* adj = (const int*)d_in[1];
    const int* etype = (const int*)d_in[2];
    const int* ntype = (const int*)d_in[3];
    // d_in[4] src_type, d_in[5] dst_type: unused by the reference math
    const float* Wk = (const float*)d_in[6];
    const float* Wq = (const float*)d_in[7];
    const float* Wv = (const float*)d_in[8];
    const float* Wa = (const float*)d_in[9];
    const float* pri = (const float*)d_in[10];
    const float* att = (const float*)d_in[11];
    const float* msg = (const float*)d_in[12];
    const float* skip = (const float*)d_in[13];
    float* out = (float*)d_out;

    float* wsf = (float*)d_ws;
    int* wsi = (int*)d_ws + OFF_INT;
    float* kb = wsf + OFF_K;
    float* qb = wsf + OFF_Q;
    float* vb = wsf + OFF_V;
    float* ab = wsf + OFF_AGG;
    float* esc = wsf + OFF_ESC;
    float* smax = wsf + OFF_SMAX;
    float* ssum = wsf + OFF_SSUM;

    init_kernel<<<(N_NODES * DIM + 255) / 256, 256, 0, stream>>>(wsf, wsi);
    hist_kernel<<<GRID_E, 256, 0, stream>>>(ntype, etype, wsi);
    offsets_kernel<<<1, 1, 0, stream>>>(wsi);
    scatter_kernel<<<GRID_E, 256, 0, stream>>>(ntype, etype, wsi);
    kqv_kernel<<<KQV_GRID, 256, 0, stream>>>(h, ntype, Wk, Wq, Wv,
                                             wsi + IO_NLIST, kb, qb, vb);
    score_kernel<<<EDGE_GRID, 256, 0, stream>>>(kb, qb, att, pri, adj, etype,
                                                wsi + IO_ELIST, esc, smax);
    expsum_kernel<<<GRID_E, 256, 0, stream>>>(adj, etype, esc, smax, ssum);
    agg_kernel<<<EDGE_GRID, 256, 0, stream>>>(vb, msg, adj, etype,
                                              wsi + IO_ELIST, esc, ssum, ab);
    out_kernel<<<KQV_GRID, 256, 0, stream>>>(ab, ntype, Wa, skip,
                                             wsi + IO_NLIST, out);
}

// Round 3
// 1094.277 us; speedup vs baseline: 5.2184x; 1.3652x over previous
//
#include <hip/hip_runtime.h>
#include <math.h>

// ---------------------------------------------------------------------------
// HGT layer slice, fp32 with bf16 edge-message buffer.
//
// R2 post-mortem: agg_kernel's 64M per-element global fp32 atomicAdds wrote
// ~1 GB to HBM (write-through RMW) -> 900 us. R3: two-phase atomic-free agg:
//   phase 1: rel-bucketed tile GEMM writes alpha*(v[src]@M[rel]) as bf16
//            rows into Y[e] (coalesced plain stores)
//   phase 2: dst-CSR gather sums Y rows per dst, single write to agg.
//
// Pipeline: init -> hist (type/rel LDS-agg + dst counts) -> offsets(1thr) ->
// dst_scan(1 blk) -> scatter (type/rel LDS-rank + dst CSR) -> kqv -> score ->
// expsum -> agg1 -> gather -> out.
// ---------------------------------------------------------------------------

#define N_NODES 50000
#define N_EDGES 500000
#define DIM 128
#define TT 8
#define RR 8
#define SEGS (N_NODES * RR)
#define CH 32
#define RSQRT_DK 0.08838834764831845f

#define KQV_GRID 1571               // 1571*32 = 50272 >= 50000 + 8*31
#define EDGE_GRID 15633             // 15633*32 = 500256 >= 500000 + 8*31
#define NODE_LIST_LEN (KQV_GRID * CH)
#define EDGE_LIST_LEN (EDGE_GRID * CH)
#define GRID_E ((N_EDGES + 255) / 256)   // 1954, also covers N

// float-index offsets into ws
#define OFF_K 0
#define OFF_Q 6400000
#define OFF_V 12800000
#define OFF_AGG 19200000
#define OFF_ESC 25600000
#define OFF_SMAX 26100000
#define OFF_SSUM 26500000
#define OFF_INT 26900000            // int region start (4B units)
// int offsets relative to (int*)ws + OFF_INT
#define IO_NLIST 0
#define IO_ELIST NODE_LIST_LEN                 // 50272
#define IO_CNT_N (IO_ELIST + EDGE_LIST_LEN)    // 550528
#define IO_CUR_N (IO_CNT_N + 8)
#define IO_POFF_N (IO_CUR_N + 8)
#define IO_CNT_E (IO_POFF_N + 16)
#define IO_CUR_E (IO_CNT_E + 8)
#define IO_POFF_E (IO_CUR_E + 8)               // 550576 (+16)
#define IO_DCNT 550592
#define IO_DCUR 600592
#define IO_DOFF 650592
#define IO_DLIST 700592                        // +500000 -> ends 1200592
// bf16 edge-message buffer Y: 500000 rows x 64 uints (2 bf16 per uint)
#define OFF_Y 28200000              // uint index; OFF_INT+1200592=28100592 < this
// total ws: (28200000 + 32000000) * 4 B = 240.8 MB

__device__ inline void atomicMaxFloat(float* addr, float val) {
    if (val >= 0.f)
        atomicMax((int*)addr, __float_as_int(val));
    else
        atomicMin((unsigned int*)addr, (unsigned int)__float_as_int(val));
}

__device__ inline unsigned int bf16pack(float lo, float hi) {
    unsigned int ul = __float_as_uint(lo);
    unsigned int uh = __float_as_uint(hi);
    ul = (ul + 0x7FFFu + ((ul >> 16) & 1u)) >> 16;   // RNE
    uh = (uh + 0x7FFFu + ((uh >> 16) & 1u)) >> 16;
    return (uh << 16) | (ul & 0xFFFFu);
}

__global__ void init_kernel(float* wsf, int* wsi) {
    int i = blockIdx.x * blockDim.x + threadIdx.x;
    if (i < SEGS) {
        wsf[OFF_SMAX + i] = __int_as_float((int)0xFF800000u);  // -inf
        wsf[OFF_SSUM + i] = 0.f;
    }
    if (i < NODE_LIST_LEN) wsi[IO_NLIST + i] = -1;
    if (i < EDGE_LIST_LEN) wsi[IO_ELIST + i] = -1;
    if (i < 64) wsi[IO_CNT_N + i] = 0;
    if (i < 2 * N_NODES) wsi[IO_DCNT + i] = 0;  // dcnt + dcur (contiguous)
}

// type/rel hist LDS-aggregated; dst hist direct (500k atomics over 50k words)
__global__ void hist_kernel(const int* __restrict__ ntype,
                            const int* __restrict__ etype,
                            const int* __restrict__ adj, int* wsi) {
    __shared__ int cn[TT], ce[RR];
    int tid = threadIdx.x;
    if (tid < TT) cn[tid] = 0;
    if (tid >= TT && tid < TT + RR) ce[tid - TT] = 0;
    __syncthreads();
    int i = blockIdx.x * blockDim.x + tid;
    if (i < N_NODES) atomicAdd(&cn[ntype[i]], 1);
    if (i < N_EDGES) {
        atomicAdd(&ce[etype[i]], 1);
        atomicAdd(&wsi[IO_DCNT + adj[N_EDGES + i]], 1);
    }
    __syncthreads();
    if (tid < TT && cn[tid] > 0) atomicAdd(&wsi[IO_CNT_N + tid], cn[tid]);
    if (tid >= TT && tid < TT + RR && ce[tid - TT] > 0)
        atomicAdd(&wsi[IO_CNT_E + tid - TT], ce[tid - TT]);
}

__global__ void offsets_kernel(int* wsi) {
    int off = 0;
    for (int t = 0; t < TT; ++t) {
        wsi[IO_POFF_N + t] = off;
        off += ((wsi[IO_CNT_N + t] + CH - 1) / CH) * CH;
    }
    wsi[IO_POFF_N + TT] = off;
    off = 0;
    for (int r = 0; r < RR; ++r) {
        wsi[IO_POFF_E + r] = off;
        off += ((wsi[IO_CNT_E + r] + CH - 1) / CH) * CH;
    }
    wsi[IO_POFF_E + RR] = off;
}

// exclusive scan of the 50k dst counts: one block, 256 threads, chunked
__global__ __launch_bounds__(256) void dst_scan_kernel(int* wsi) {
    __shared__ int part[256];
    int tid = threadIdx.x;
    const int CHUNK = (N_NODES + 255) / 256;  // 196
    int base = tid * CHUNK;
    int s = 0;
    for (int i = 0; i < CHUNK; ++i) {
        int idx = base + i;
        if (idx < N_NODES) s += wsi[IO_DCNT + idx];
    }
    part[tid] = s;
    __syncthreads();
    for (int off = 1; off < 256; off <<= 1) {
        int t = (tid >= off) ? part[tid - off] : 0;
        __syncthreads();
        part[tid] += t;
        __syncthreads();
    }
    int run = part[tid] - s;  // exclusive prefix of this chunk
    for (int i = 0; i < CHUNK; ++i) {
        int idx = base + i;
        if (idx < N_NODES) {
            int c = wsi[IO_DCNT + idx];
            wsi[IO_DOFF + idx] = run;
            run += c;
        }
    }
}

__global__ void scatter_kernel(const int* __restrict__ ntype,
                               const int* __restrict__ etype,
                               const int* __restrict__ adj, int* wsi) {
    __shared__ int cn[TT], ce[RR], bn[TT], be[RR];
    int tid = threadIdx.x;
    if (tid < TT) cn[tid] = 0;
    if (tid >= TT && tid < TT + RR) ce[tid - TT] = 0;
    __syncthreads();
    int i = blockIdx.x * blockDim.x + tid;
    int t = -1, rnk_n = 0, r = -1, rnk_e = 0;
    if (i < N_NODES) {
        t = ntype[i];
        rnk_n = atomicAdd(&cn[t], 1);
    }
    if (i < N_EDGES) {
        r = etype[i];
        rnk_e = atomicAdd(&ce[r], 1);
    }
    __syncthreads();
    if (tid < TT && cn[tid] > 0) bn[tid] = atomicAdd(&wsi[IO_CUR_N + tid], cn[tid]);
    if (tid >= TT && tid < TT + RR && ce[tid - TT] > 0)
        be[tid - TT] = atomicAdd(&wsi[IO_CUR_E + tid - TT], ce[tid - TT]);
    __syncthreads();
    if (t >= 0)
        wsi[IO_NLIST + wsi[IO_POFF_N + t] + bn[t] + rnk_n] = i;
    if (r >= 0) {
        wsi[IO_ELIST + wsi[IO_POFF_E + r] + be[r] + rnk_e] = i;
        int d = adj[N_EDGES + i];
        int pos = wsi[IO_DOFF + d] + atomicAdd(&wsi[IO_DCUR + d], 1);
        wsi[IO_DLIST + pos] = i;
    }
}

// --- tile GEMM kernels: 256 threads, 32 rows x 128 cols, K=128 -------------

__global__ __launch_bounds__(256) void kqv_kernel(
    const float* __restrict__ h, const int* __restrict__ ntype,
    const float* __restrict__ Wk, const float* __restrict__ Wq,
    const float* __restrict__ Wv, const int* __restrict__ nlist,
    float* __restrict__ kout, float* __restrict__ qout,
    float* __restrict__ vout) {
    __shared__ float hl[CH][DIM + 4];
    __shared__ int nid[CH];
    int tid = threadIdx.x;
    int base = blockIdx.x * CH;
    if (tid < CH) nid[tid] = nlist[base + tid];
    __syncthreads();
    int first = -1;
#pragma unroll
    for (int j = 0; j < CH; ++j)
        if (first < 0 && nid[j] >= 0) first = nid[j];
    if (first < 0) return;
    int t = ntype[first];

    for (int r2 = 0; r2 < CH; r2 += 2) {
        int row = r2 + (tid >> 7);
        int col = tid & 127;
        int n = nid[row];
        if (n < 0) n = 0;
        hl[row][col] = h[(size_t)n * DIM + col];
    }
    __syncthreads();
    int te = tid >> 5, tc = tid & 31;

#pragma unroll
    for (int w = 0; w < 3; ++w) {
        const float* W = (w == 0 ? Wk : (w == 1 ? Wq : Wv)) + (size_t)t * DIM * DIM;
        const float4* W4 = (const float4*)W;
        float* O = (w == 0 ? kout : (w == 1 ? qout : vout));
        float acc[4][4] = {};
        for (int i = 0; i < DIM; ++i) {
            float4 a = W4[i * 32 + tc];
#pragma unroll
            for (int j = 0; j < 4; ++j) {
                float hv = hl[te * 4 + j][i];
                acc[j][0] += hv * a.x;
                acc[j][1] += hv * a.y;
                acc[j][2] += hv * a.z;
                acc[j][3] += hv * a.w;
            }
        }
#pragma unroll
        for (int j = 0; j < 4; ++j) {
            int n = nid[te * 4 + j];
            if (n >= 0) {
                float4 o = make_float4(acc[j][0], acc[j][1], acc[j][2], acc[j][3]);
                ((float4*)(O + (size_t)n * DIM))[tc] = o;
            }
        }
    }
}

__global__ __launch_bounds__(256) void score_kernel(
    const float* __restrict__ kbuf, const float* __restrict__ qbuf,
    const float* __restrict__ att, const float* __restrict__ pri,
    const int* __restrict__ adj, const int* __restrict__ etype,
    const int* __restrict__ elist, float* __restrict__ esc,
    float* __restrict__ smax) {
    __shared__ float kl[CH][DIM + 4];
    __shared__ int eid[CH], es[CH], ed[CH];
    int tid = threadIdx.x;
    int base = blockIdx.x * CH;
    if (tid < CH) {
        int e = elist[base + tid];
        eid[tid] = e;
        es[tid] = (e >= 0) ? adj[e] : 0;
        ed[tid] = (e >= 0) ? adj[N_EDGES + e] : 0;
    }
    __syncthreads();
    int firste = -1;
#pragma unroll
    for (int j = 0; j < CH; ++j)
        if (firste < 0 && eid[j] >= 0) firste = eid[j];
    if (firste < 0) return;
    int rel = etype[firste];

    for (int r2 = 0; r2 < CH; r2 += 2) {
        int row = r2 + (tid >> 7);
        int col = tid & 127;
        kl[row][col] = kbuf[(size_t)es[row] * DIM + col];
    }
    __syncthreads();
    int te = tid >> 5, tc = tid & 31;
    const float4* A4 = (const float4*)(att + (size_t)rel * DIM * DIM);
    float acc[4][4] = {};
    for (int i = 0; i < DIM; ++i) {
        float4 a = A4[i * 32 + tc];
#pragma unroll
        for (int j = 0; j < 4; ++j) {
            float kv = kl[te * 4 + j][i];
            acc[j][0] += kv * a.x;
            acc[j][1] += kv * a.y;
            acc[j][2] += kv * a.z;
            acc[j][3] += kv * a.w;
        }
    }
    float prv = pri[rel] * RSQRT_DK;
#pragma unroll
    for (int j = 0; j < 4; ++j) {
        int erow = te * 4 + j;
        int dstn = ed[erow];
        float4 qv = ((const float4*)(qbuf + (size_t)dstn * DIM))[tc];
        float p = acc[j][0] * qv.x + acc[j][1] * qv.y + acc[j][2] * qv.z +
                  acc[j][3] * qv.w;
        p += __shfl_down(p, 16, 32);
        p += __shfl_down(p, 8, 32);
        p += __shfl_down(p, 4, 32);
        p += __shfl_down(p, 2, 32);
        p += __shfl_down(p, 1, 32);
        if (tc == 0) {
            int e = eid[erow];
            if (e >= 0) {
                float s = p * prv;
                esc[e] = s;
                atomicMaxFloat(&smax[(size_t)dstn * RR + rel], s);
            }
        }
    }
}

__global__ void expsum_kernel(const int* __restrict__ adj,
                              const int* __restrict__ etype,
                              float* __restrict__ esc,
                              const float* __restrict__ smax,
                              float* __restrict__ ssum) {
    int e = blockIdx.x * blockDim.x + threadIdx.x;
    if (e < N_EDGES) {
        int dstn = adj[N_EDGES + e];
        int seg = dstn * RR + etype[e];
        float ex = __expf(esc[e] - smax[seg]);
        esc[e] = ex;
        atomicAdd(&ssum[seg], ex);
    }
}

// phase 1: alpha*(v[src]@M[rel]) -> bf16 rows Y[e], plain coalesced stores
__global__ __launch_bounds__(256) void agg1_kernel(
    const float* __restrict__ vbuf, const float* __restrict__ msg,
    const int* __restrict__ adj, const int* __restrict__ etype,
    const int* __restrict__ elist, const float* __restrict__ esc,
    const float* __restrict__ ssum, unsigned int* __restrict__ Y) {
    __shared__ float vl[CH][DIM + 4];
    __shared__ int eid[CH], es[CH], ed[CH];
    int tid = threadIdx.x;
    int base = blockIdx.x * CH;
    if (tid < CH) {
        int e = elist[base + tid];
        eid[tid] = e;
        es[tid] = (e >= 0) ? adj[e] : 0;
        ed[tid] = (e >= 0) ? adj[N_EDGES + e] : 0;
    }
    __syncthreads();
    int firste = -1;
#pragma unroll
    for (int j = 0; j < CH; ++j)
        if (firste < 0 && eid[j] >= 0) firste = eid[j];
    if (firste < 0) return;
    int rel = etype[firste];

    for (int r2 = 0; r2 < CH; r2 += 2) {
        int row = r2 + (tid >> 7);
        int col = tid & 127;
        vl[row][col] = vbuf[(size_t)es[row] * DIM + col];
    }
    __syncthreads();
    int te = tid >> 5, tc = tid & 31;
    const float4* M4 = (const float4*)(msg + (size_t)rel * DIM * DIM);
    float acc[4][4] = {};
    for (int i = 0; i < DIM; ++i) {
        float4 a = M4[i * 32 + tc];
#pragma unroll
        for (int j = 0; j < 4; ++j) {
            float vv = vl[te * 4 + j][i];
            acc[j][0] += vv * a.x;
            acc[j][1] += vv * a.y;
            acc[j][2] += vv * a.z;
            acc[j][3] += vv * a.w;
        }
    }
#pragma unroll
    for (int j = 0; j < 4; ++j) {
        int erow = te * 4 + j;
        int e = eid[erow];
        if (e >= 0) {
            int dstn = ed[erow];
            float alpha = esc[e] / ssum[(size_t)dstn * RR + rel];
            uint2 p;
            p.x = bf16pack(acc[j][0] * alpha, acc[j][1] * alpha);
            p.y = bf16pack(acc[j][2] * alpha, acc[j][3] * alpha);
            ((uint2*)(Y + (size_t)e * 64))[tc] = p;
        }
    }
}

// phase 2: one wave per dst, sum Y rows, single agg write (covers all nodes)
__global__ __launch_bounds__(256) void gather_kernel(
    const unsigned int* __restrict__ Y, const int* __restrict__ dlist,
    const int* __restrict__ doff, const int* __restrict__ dcnt,
    float* __restrict__ agg) {
    int wv = threadIdx.x >> 6, lane = threadIdx.x & 63;
    int dst = blockIdx.x * 4 + wv;
    if (dst >= N_NODES) return;
    int beg = doff[dst], cnt = dcnt[dst];
    float a0 = 0.f, a1 = 0.f;
    for (int j = 0; j < cnt; ++j) {
        int e = dlist[beg + j];
        unsigned int u = Y[(size_t)e * 64 + lane];
        a0 += __uint_as_float(u << 16);
        a1 += __uint_as_float(u & 0xFFFF0000u);
    }
    ((float2*)(agg + (size_t)dst * DIM))[lane] = make_float2(a0, a1);
}

__global__ __launch_bounds__(256) void out_kernel(
    const float* __restrict__ agg, const int* __restrict__ ntype,
    const float* __restrict__ Wa, const float* __restrict__ skip,
    const int* __restrict__ nlist, float* __restrict__ out) {
    __shared__ float gl[CH][DIM + 4];
    __shared__ int nid[CH];
    int tid = threadIdx.x;
    int base = blockIdx.x * CH;
    if (tid < CH) nid[tid] = nlist[base + tid];
    __syncthreads();
    int first = -1;
#pragma unroll
    for (int j = 0; j < CH; ++j)
        if (first < 0 && nid[j] >= 0) first = nid[j];
    if (first < 0) return;
    int t = ntype[first];
    float sig = 1.f / (1.f + __expf(-skip[t]));

    for (int r2 = 0; r2 < CH; r2 += 2) {
        int row = r2 + (tid >> 7);
        int col = tid & 127;
        int n = nid[row];
        if (n < 0) n = 0;
        gl[row][col] = agg[(size_t)n * DIM + col];
    }
    __syncthreads();
    int te = tid >> 5, tc = tid & 31;
    const float4* W4 = (const float4*)(Wa + (size_t)t * DIM * DIM);
    float acc[4][4] = {};
    for (int i = 0; i < DIM; ++i) {
        float4 a = W4[i * 32 + tc];
#pragma unroll
        for (int j = 0; j < 4; ++j) {
            float gv = gl[te * 4 + j][i];
            acc[j][0] += gv * a.x;
            acc[j][1] += gv * a.y;
            acc[j][2] += gv * a.z;
            acc[j][3] += gv * a.w;
        }
    }
#pragma unroll
    for (int j = 0; j < 4; ++j) {
        int n = nid[te * 4 + j];
        if (n >= 0) {
            float4 o = make_float4(acc[j][0] * sig, acc[j][1] * sig,
                                   acc[j][2] * sig, acc[j][3] * sig);
            ((float4*)(out + (size_t)n * DIM))[tc] = o;
        }
    }
}

extern "C" void kernel_launch(void* const* d_in, const int* in_sizes, int n_in,
                              void* d_out, int out_size, void* d_ws,
                              size_t ws_size, hipStream_t stream) {
    const float* h = (const float*)d_in[0];
    const int* adj = (const int*)d_in[1];
    const int* etype = (const int*)d_in[2];
    const int* ntype = (const int*)d_in[3];
    const float* Wk = (const float*)d_in[6];
    const float* Wq = (const float*)d_in[7];
    const float* Wv = (const float*)d_in[8];
    const float* Wa = (const float*)d_in[9];
    const float* pri = (const float*)d_in[10];
    const float* att = (const float*)d_in[11];
    const float* msg = (const float*)d_in[12];
    const float* skip = (const float*)d_in[13];
    float* out = (float*)d_out;

    float* wsf = (float*)d_ws;
    int* wsi = (int*)d_ws + OFF_INT;
    unsigned int* Y = (unsigned int*)d_ws + OFF_Y;
    float* kb = wsf + OFF_K;
    float* qb = wsf + OFF_Q;
    float* vb = wsf + OFF_V;
    float* ab = wsf + OFF_AGG;
    float* esc = wsf + OFF_ESC;
    float* smax = wsf + OFF_SMAX;
    float* ssum = wsf + OFF_SSUM;

    init_kernel<<<(EDGE_LIST_LEN + 255) / 256, 256, 0, stream>>>(wsf, wsi);
    hist_kernel<<<GRID_E, 256, 0, stream>>>(ntype, etype, adj, wsi);
    offsets_kernel<<<1, 1, 0, stream>>>(wsi);
    dst_scan_kernel<<<1, 256, 0, stream>>>(wsi);
    scatter_kernel<<<GRID_E, 256, 0, stream>>>(ntype, etype, adj, wsi);
    kqv_kernel<<<KQV_GRID, 256, 0, stream>>>(h, ntype, Wk, Wq, Wv,
                                             wsi + IO_NLIST, kb, qb, vb);
    score_kernel<<<EDGE_GRID, 256, 0, stream>>>(kb, qb, att, pri, adj, etype,
                                                wsi + IO_ELIST, esc, smax);
    expsum_kernel<<<GRID_E, 256, 0, stream>>>(adj, etype, esc, smax, ssum);
    agg1_kernel<<<EDGE_GRID, 256, 0, stream>>>(vb, msg, adj, etype,
                                               wsi + IO_ELIST, esc, ssum, Y);
    gather_kernel<<<(N_NODES + 3) / 4, 256, 0, stream>>>(
        Y, wsi + IO_DLIST, wsi + IO_DOFF, wsi + IO_DCNT, ab);
    out_kernel<<<KQV_GRID, 256, 0, stream>>>(ab, ntype, Wa, skip,
                                             wsi + IO_NLIST, out);
}

// Round 5
// 722.668 us; speedup vs baseline: 7.9017x; 1.5142x over previous
//
#include <hip/hip_runtime.h>
#include <math.h>

// ---------------------------------------------------------------------------
// HGT layer slice. R5: R4 structure with the ws-layout bug fixed.
//
// R4 post-mortem: attF needs 65,536 words but got 40,000; msgT then also
// overran OFF_INT and corrupted nlist -> wild OOB gathers -> NaN. Offsets
// below recomputed and margin-checked.
//
// score_e = k_src . (att_r @ q_dst), vM_e = v_src @ msg_r depend only on
// (node, rel): precompute U[n,r,:] = q_n @ att_r^T and VM[n,r,:] = v_n @ msg_r
// as dense f16 MFMA GEMMs, then the edge phase is gather + 128-dot and
// aggregation gathers VM[src,rel] * alpha directly.
//
// Pipeline: init -> convert -> hist -> offsets -> dst_scan -> scatter ->
// kqv (f16 out) -> U gemm -> VM gemm -> escore -> expsum -> gather -> out.
// ---------------------------------------------------------------------------

#define N_NODES 50000
#define N_EDGES 500000
#define DIM 128
#define TT 8
#define RR 8
#define SEGS (N_NODES * RR)
#define CH 32
#define RSQRT_DK 0.08838834764831845f

#define KQV_GRID 1571               // 1571*32 = 50272 >= 50000 + 8*31
#define NODE_LIST_LEN (KQV_GRID * CH)
#define GRID_E ((N_EDGES + 255) / 256)   // 1954, also covers N
#define GEMM_ROWBLKS ((N_NODES + 127) / 128)  // 391

// word offsets into ws (4B units); _Float16 index = 2*word
// sizes (words): U 25.6M | VM 25.6M | kF 3.2M | aggF 3.2M | esc 0.5M |
// smax 0.4M | ssum 0.4M | attF 65,536 | msgT 65,536 | int 700,304
#define OFF_U 0                    // UF16 [n][8][128], ends 25,600,000
#define OFF_VM 25600000            // VMF16 [n][8][128], ends 51,200,000
#define OFF_QF 25600000            // alias: qF16 [n][128] (dead before VM write)
#define OFF_KF 51200000            // ends 54,400,000
#define OFF_AGGF 54400000          // ends 57,600,000
#define OFF_VF 54400000            // alias: vF16 (dead before gather writes agg)
#define OFF_ESC 57600000           // fp32 [E], ends 58,100,000
#define OFF_SMAX 58100000          // fp32 [SEGS], ends 58,500,000
#define OFF_SSUM 58500000          // fp32 [SEGS], ends 58,900,000
#define OFF_ATTF 58900000          // f16 [8][128][128] = 65,536 words, ends 58,965,536
#define OFF_MSGT 58970000          // f16 [8][128][128] transposed, ends 59,035,536
#define OFF_INT 59040000           // int region, ends 59,740,304 (239.0 MB)
#define IO_NLIST 0
#define IO_CNT_N 50272
#define IO_CUR_N 50280
#define IO_POFF_N 50288
#define IO_DCNT 50304
#define IO_DCUR 100304
#define IO_DOFF 150304
#define IO_DLIST 200304            // +500000 -> end 700304 words

typedef _Float16 half8 __attribute__((ext_vector_type(8)));
typedef _Float16 half4 __attribute__((ext_vector_type(4)));
typedef _Float16 half2t __attribute__((ext_vector_type(2)));
typedef float f32x4 __attribute__((ext_vector_type(4)));

__device__ inline void atomicMaxFloat(float* addr, float val) {
    if (val >= 0.f)
        atomicMax((int*)addr, __float_as_int(val));
    else
        atomicMin((unsigned int*)addr, (unsigned int)__float_as_int(val));
}

__global__ void init_kernel(float* wsf, int* wsi) {
    int i = blockIdx.x * blockDim.x + threadIdx.x;
    if (i < SEGS) {
        wsf[OFF_SMAX + i] = __int_as_float((int)0xFF800000u);  // -inf
        wsf[OFF_SSUM + i] = 0.f;
    }
    if (i < NODE_LIST_LEN) wsi[IO_NLIST + i] = -1;
    if (i < 100000) wsi[IO_DCNT + i] = 0;   // dcnt+dcur contiguous
    if (i < 32) wsi[IO_CNT_N + i] = 0;      // cnt/cur/poff
}

// att fp32 -> f16 straight; msg fp32 -> f16 transposed to [r][f][d]
__global__ void convert_kernel(const float* __restrict__ att,
                               const float* __restrict__ msg,
                               _Float16* __restrict__ attF,
                               _Float16* __restrict__ msgT) {
    int i = blockIdx.x * 256 + threadIdx.x;
    if (i < RR * DIM * DIM) {
        attF[i] = (_Float16)att[i];
        int r = i >> 14, d = (i >> 7) & 127, f = i & 127;
        msgT[(r << 14) + (f << 7) + d] = (_Float16)msg[i];
    }
}

__global__ void hist_kernel(const int* __restrict__ ntype,
                            const int* __restrict__ adj, int* wsi) {
    __shared__ int cn[TT];
    int tid = threadIdx.x;
    if (tid < TT) cn[tid] = 0;
    __syncthreads();
    int i = blockIdx.x * blockDim.x + tid;
    if (i < N_NODES) atomicAdd(&cn[ntype[i]], 1);
    if (i < N_EDGES) atomicAdd(&wsi[IO_DCNT + adj[N_EDGES + i]], 1);
    __syncthreads();
    if (tid < TT && cn[tid] > 0) atomicAdd(&wsi[IO_CNT_N + tid], cn[tid]);
}

__global__ void offsets_kernel(int* wsi) {
    int off = 0;
    for (int t = 0; t < TT; ++t) {
        wsi[IO_POFF_N + t] = off;
        off += ((wsi[IO_CNT_N + t] + CH - 1) / CH) * CH;
    }
}

__global__ __launch_bounds__(256) void dst_scan_kernel(int* wsi) {
    __shared__ int part[256];
    int tid = threadIdx.x;
    const int CHUNK = (N_NODES + 255) / 256;
    int base = tid * CHUNK;
    int s = 0;
    for (int i = 0; i < CHUNK; ++i) {
        int idx = base + i;
        if (idx < N_NODES) s += wsi[IO_DCNT + idx];
    }
    part[tid] = s;
    __syncthreads();
    for (int off = 1; off < 256; off <<= 1) {
        int t = (tid >= off) ? part[tid - off] : 0;
        __syncthreads();
        part[tid] += t;
        __syncthreads();
    }
    int run = part[tid] - s;
    for (int i = 0; i < CHUNK; ++i) {
        int idx = base + i;
        if (idx < N_NODES) {
            int c = wsi[IO_DCNT + idx];
            wsi[IO_DOFF + idx] = run;
            run += c;
        }
    }
}

__global__ void scatter_kernel(const int* __restrict__ ntype,
                               const int* __restrict__ adj, int* wsi) {
    __shared__ int cn[TT], bn[TT];
    int tid = threadIdx.x;
    if (tid < TT) cn[tid] = 0;
    __syncthreads();
    int i = blockIdx.x * blockDim.x + tid;
    int t = -1, rnk = 0;
    if (i < N_NODES) {
        t = ntype[i];
        rnk = atomicAdd(&cn[t], 1);
    }
    __syncthreads();
    if (tid < TT && cn[tid] > 0) bn[tid] = atomicAdd(&wsi[IO_CUR_N + tid], cn[tid]);
    __syncthreads();
    if (t >= 0)
        wsi[IO_NLIST + wsi[IO_POFF_N + t] + bn[t] + rnk] = i;
    if (i < N_EDGES) {
        int d = adj[N_EDGES + i];
        int pos = wsi[IO_DOFF + d] + atomicAdd(&wsi[IO_DCUR + d], 1);
        wsi[IO_DLIST + pos] = i;
    }
}

// kqv: type-bucketed 32-node tile GEMM, fp32 math, f16 output rows
__global__ __launch_bounds__(256) void kqv_kernel(
    const float* __restrict__ h, const int* __restrict__ ntype,
    const float* __restrict__ Wk, const float* __restrict__ Wq,
    const float* __restrict__ Wv, const int* __restrict__ nlist,
    _Float16* __restrict__ kout, _Float16* __restrict__ qout,
    _Float16* __restrict__ vout) {
    __shared__ float hl[CH][DIM + 4];
    __shared__ int nid[CH];
    int tid = threadIdx.x;
    int base = blockIdx.x * CH;
    if (tid < CH) nid[tid] = nlist[base + tid];
    __syncthreads();
    int first = -1;
#pragma unroll
    for (int j = 0; j < CH; ++j)
        if (first < 0 && nid[j] >= 0) first = nid[j];
    if (first < 0) return;
    int t = ntype[first];

    for (int r2 = 0; r2 < CH; r2 += 2) {
        int row = r2 + (tid >> 7);
        int col = tid & 127;
        int n = nid[row];
        if (n < 0) n = 0;
        hl[row][col] = h[(size_t)n * DIM + col];
    }
    __syncthreads();
    int te = tid >> 5, tc = tid & 31;

#pragma unroll
    for (int w = 0; w < 3; ++w) {
        const float* W = (w == 0 ? Wk : (w == 1 ? Wq : Wv)) + (size_t)t * DIM * DIM;
        const float4* W4 = (const float4*)W;
        _Float16* O = (w == 0 ? kout : (w == 1 ? qout : vout));
        float acc[4][4] = {};
        for (int i = 0; i < DIM; ++i) {
            float4 a = W4[i * 32 + tc];
#pragma unroll
            for (int j = 0; j < 4; ++j) {
                float hv = hl[te * 4 + j][i];
                acc[j][0] += hv * a.x;
                acc[j][1] += hv * a.y;
                acc[j][2] += hv * a.z;
                acc[j][3] += hv * a.w;
            }
        }
#pragma unroll
        for (int j = 0; j < 4; ++j) {
            int n = nid[te * 4 + j];
            if (n >= 0) {
                half4 o;
                o[0] = (_Float16)acc[j][0];
                o[1] = (_Float16)acc[j][1];
                o[2] = (_Float16)acc[j][2];
                o[3] = (_Float16)acc[j][3];
                *(half4*)(O + (size_t)n * DIM + tc * 4) = o;
            }
        }
    }
}

// Dense MFMA GEMM: Out[n, rel, col] = sum_k A[n,k] * B[rel, col, k]
// (B stored "col-major": 8 contiguous k per fragment). Used for both
// U (A=qF16, B=attF16 as [r][d][f], k=f, col=d) and
// VM (A=vF16, B=msgT as [r][f][d], k=d, col=f).
// MFMA 16x16x32 f16 layouts: A[m=lane&15][k=quad*8+j], B[k=quad*8+j][n=lane&15],
// D col=lane&15, row=quad*4+reg.
__global__ __launch_bounds__(256) void nr_gemm_kernel(
    const _Float16* __restrict__ A, const _Float16* __restrict__ B,
    _Float16* __restrict__ Of) {
    int rel = blockIdx.y;
    int tid = threadIdx.x;
    int wv = tid >> 6, lane = tid & 63;
    int l16 = lane & 15, quad = lane >> 4;
    int row0 = blockIdx.x * 128 + wv * 32;
    const _Float16* Bbase = B + rel * DIM * DIM;
    f32x4 acc[2][8];
#pragma unroll
    for (int m = 0; m < 2; ++m)
#pragma unroll
        for (int c = 0; c < 8; ++c) acc[m][c] = (f32x4){0.f, 0.f, 0.f, 0.f};

    for (int kk = 0; kk < 4; ++kk) {
        int kb = kk * 32 + quad * 8;
        half8 a[2];
#pragma unroll
        for (int m = 0; m < 2; ++m) {
            int node = row0 + m * 16 + l16;
            if (node < N_NODES)
                a[m] = *(const half8*)(A + (size_t)node * DIM + kb);
            else
                a[m] = (half8){0, 0, 0, 0, 0, 0, 0, 0};
        }
#pragma unroll
        for (int c = 0; c < 8; ++c) {
            half8 b = *(const half8*)(Bbase + (c * 16 + l16) * DIM + kb);
#pragma unroll
            for (int m = 0; m < 2; ++m)
                acc[m][c] = __builtin_amdgcn_mfma_f32_16x16x32_f16(
                    a[m], b, acc[m][c], 0, 0, 0);
        }
    }
#pragma unroll
    for (int m = 0; m < 2; ++m)
#pragma unroll
        for (int c = 0; c < 8; ++c)
#pragma unroll
            for (int rg = 0; rg < 4; ++rg) {
                int node = row0 + m * 16 + quad * 4 + rg;
                if (node < N_NODES)
                    Of[((size_t)node * RR + rel) * DIM + c * 16 + l16] =
                        (_Float16)acc[m][c][rg];
            }
}

// per-edge score: 16 lanes per edge, dot(kF16[src], UF16[dst,rel])
__global__ __launch_bounds__(256) void escore_kernel(
    const _Float16* __restrict__ kF, const _Float16* __restrict__ UF,
    const float* __restrict__ pri, const int* __restrict__ adj,
    const int* __restrict__ etype, float* __restrict__ esc,
    float* __restrict__ smax) {
    int tid = threadIdx.x;
    int e = blockIdx.x * 16 + (tid >> 4);
    if (e >= N_EDGES) return;
    int l = tid & 15;
    int src = adj[e], dst = adj[N_EDGES + e], r = etype[e];
    half8 k8 = *(const half8*)(kF + (size_t)src * DIM + l * 8);
    half8 u8 = *(const half8*)(UF + ((size_t)dst * RR + r) * DIM + l * 8);
    float p = 0.f;
#pragma unroll
    for (int j = 0; j < 8; ++j) p += (float)k8[j] * (float)u8[j];
    p += __shfl_down(p, 8, 16);
    p += __shfl_down(p, 4, 16);
    p += __shfl_down(p, 2, 16);
    p += __shfl_down(p, 1, 16);
    if (l == 0) {
        float s = p * pri[r] * RSQRT_DK;
        esc[e] = s;
        atomicMaxFloat(&smax[(size_t)dst * RR + r], s);
    }
}

__global__ void expsum_kernel(const int* __restrict__ adj,
                              const int* __restrict__ etype,
                              float* __restrict__ esc,
                              const float* __restrict__ smax,
                              float* __restrict__ ssum) {
    int e = blockIdx.x * blockDim.x + threadIdx.x;
    if (e < N_EDGES) {
        int dstn = adj[N_EDGES + e];
        int seg = dstn * RR + etype[e];
        float ex = __expf(esc[e] - smax[seg]);
        esc[e] = ex;
        atomicAdd(&ssum[seg], ex);
    }
}

// one wave per dst: agg = sum alpha_e * VM[src_e, rel_e]; writes f16 row
__global__ __launch_bounds__(256) void gather_kernel(
    const _Float16* __restrict__ VMF, const int* __restrict__ dlist,
    const int* __restrict__ doff, const int* __restrict__ dcnt,
    const int* __restrict__ adj, const int* __restrict__ etype,
    const float* __restrict__ esc, const float* __restrict__ ssum,
    _Float16* __restrict__ aggF) {
    int wv = threadIdx.x >> 6, lane = threadIdx.x & 63;
    int dst = blockIdx.x * 4 + wv;
    if (dst >= N_NODES) return;
    float inv[RR];
#pragma unroll
    for (int r = 0; r < RR; ++r) {
        float s = ssum[(size_t)dst * RR + r];
        inv[r] = (s > 0.f) ? 1.f / s : 0.f;
    }
    int beg = doff[dst], cnt = dcnt[dst];
    float a0 = 0.f, a1 = 0.f;
    for (int j = 0; j < cnt; ++j) {
        int e = dlist[beg + j];
        int src = adj[e];
        int r = etype[e];
        float alpha = esc[e] * inv[r];
        half2t v2 = *(const half2t*)(VMF + ((size_t)src * RR + r) * DIM + lane * 2);
        a0 += alpha * (float)v2[0];
        a1 += alpha * (float)v2[1];
    }
    half2t o;
    o[0] = (_Float16)a0;
    o[1] = (_Float16)a1;
    *(half2t*)(aggF + (size_t)dst * DIM + lane * 2) = o;
}

// out: type-bucketed tile GEMM, reads f16 agg, fp32 math
__global__ __launch_bounds__(256) void out_kernel(
    const _Float16* __restrict__ aggF, const int* __restrict__ ntype,
    const float* __restrict__ Wa, const float* __restrict__ skip,
    const int* __restrict__ nlist, float* __restrict__ out) {
    __shared__ float gl[CH][DIM + 4];
    __shared__ int nid[CH];
    int tid = threadIdx.x;
    int base = blockIdx.x * CH;
    if (tid < CH) nid[tid] = nlist[base + tid];
    __syncthreads();
    int first = -1;
#pragma unroll
    for (int j = 0; j < CH; ++j)
        if (first < 0 && nid[j] >= 0) first = nid[j];
    if (first < 0) return;
    int t = ntype[first];
    float sig = 1.f / (1.f + __expf(-skip[t]));

    for (int r4 = 0; r4 < CH; r4 += 4) {
        int row = r4 + (tid >> 6);
        int cu = tid & 63;
        int n = nid[row];
        if (n < 0) n = 0;
        half2t v2 = *(const half2t*)(aggF + (size_t)n * DIM + cu * 2);
        gl[row][cu * 2] = (float)v2[0];
        gl[row][cu * 2 + 1] = (float)v2[1];
    }
    __syncthreads();
    int te = tid >> 5, tc = tid & 31;
    const float4* W4 = (const float4*)(Wa + (size_t)t * DIM * DIM);
    float acc[4][4] = {};
    for (int i = 0; i < DIM; ++i) {
        float4 a = W4[i * 32 + tc];
#pragma unroll
        for (int j = 0; j < 4; ++j) {
            float gv = gl[te * 4 + j][i];
            acc[j][0] += gv * a.x;
            acc[j][1] += gv * a.y;
            acc[j][2] += gv * a.z;
            acc[j][3] += gv * a.w;
        }
    }
#pragma unroll
    for (int j = 0; j < 4; ++j) {
        int n = nid[te * 4 + j];
        if (n >= 0) {
            float4 o = make_float4(acc[j][0] * sig, acc[j][1] * sig,
                                   acc[j][2] * sig, acc[j][3] * sig);
            ((float4*)(out + (size_t)n * DIM))[tc] = o;
        }
    }
}

extern "C" void kernel_launch(void* const* d_in, const int* in_sizes, int n_in,
                              void* d_out, int out_size, void* d_ws,
                              size_t ws_size, hipStream_t stream) {
    const float* h = (const float*)d_in[0];
    const int* adj = (const int*)d_in[1];
    const int* etype = (const int*)d_in[2];
    const int* ntype = (const int*)d_in[3];
    const float* Wk = (const float*)d_in[6];
    const float* Wq = (const float*)d_in[7];
    const float* Wv = (const float*)d_in[8];
    const float* Wa = (const float*)d_in[9];
    const float* pri = (const float*)d_in[10];
    const float* att = (const float*)d_in[11];
    const float* msg = (const float*)d_in[12];
    const float* skip = (const float*)d_in[13];
    float* out = (float*)d_out;

    float* wsf = (float*)d_ws;
    int* wsi = (int*)d_ws + OFF_INT;
    _Float16* wsh = (_Float16*)d_ws;
    _Float16* UF = wsh + (size_t)OFF_U * 2;
    _Float16* VMF = wsh + (size_t)OFF_VM * 2;
    _Float16* qF = wsh + (size_t)OFF_QF * 2;
    _Float16* kF = wsh + (size_t)OFF_KF * 2;
    _Float16* aggF = wsh + (size_t)OFF_AGGF * 2;
    _Float16* vF = wsh + (size_t)OFF_VF * 2;
    _Float16* attF = wsh + (size_t)OFF_ATTF * 2;
    _Float16* msgT = wsh + (size_t)OFF_MSGT * 2;
    float* esc = wsf + OFF_ESC;
    float* smax = wsf + OFF_SMAX;
    float* ssum = wsf + OFF_SSUM;

    init_kernel<<<(SEGS + 255) / 256, 256, 0, stream>>>(wsf, wsi);
    convert_kernel<<<(RR * DIM * DIM + 255) / 256, 256, 0, stream>>>(
        att, msg, attF, msgT);
    hist_kernel<<<GRID_E, 256, 0, stream>>>(ntype, adj, wsi);
    offsets_kernel<<<1, 1, 0, stream>>>(wsi);
    dst_scan_kernel<<<1, 256, 0, stream>>>(wsi);
    scatter_kernel<<<GRID_E, 256, 0, stream>>>(ntype, adj, wsi);
    kqv_kernel<<<KQV_GRID, 256, 0, stream>>>(h, ntype, Wk, Wq, Wv,
                                             wsi + IO_NLIST, kF, qF, vF);
    {
        dim3 g(GEMM_ROWBLKS, RR);
        nr_gemm_kernel<<<g, 256, 0, stream>>>(qF, attF, UF);   // U = q @ att^T
        nr_gemm_kernel<<<g, 256, 0, stream>>>(vF, msgT, VMF);  // VM = v @ msg
    }
    escore_kernel<<<(N_EDGES + 15) / 16, 256, 0, stream>>>(
        kF, UF, pri, adj, etype, esc, smax);
    expsum_kernel<<<GRID_E, 256, 0, stream>>>(adj, etype, esc, smax, ssum);
    gather_kernel<<<(N_NODES + 3) / 4, 256, 0, stream>>>(
        VMF, wsi + IO_DLIST, wsi + IO_DOFF, wsi + IO_DCNT, adj, etype, esc,
        ssum, aggF);
    out_kernel<<<KQV_GRID, 256, 0, stream>>>(aggF, ntype, Wa, skip,
                                             wsi + IO_NLIST, out);
}

// Round 7
// 678.444 us; speedup vs baseline: 8.4168x; 1.0652x over previous
//
#include <hip/hip_runtime.h>
#include <math.h>

// ---------------------------------------------------------------------------
// HGT layer slice. R7: split precision by sensitivity.
//
// R6 post-mortem: f16 MFMA for k/q added h/W rounding upstream of the
// near-argmax softmax -> absmax 22016 (4x threshold). Score path gets fp32;
// value path keeps f16/MFMA (R3 passed with coarser bf16 messages):
//  - k,q: fp32 vector tile GEMM (R5-proven), f16 outputs
//  - v: f16 MFMA; U,VM: f16 MFMA; out: f16 MFMA
//  - attend: fused score+softmax+aggregate, one wave per dst
//
// Pipeline: init -> convert -> hconv -> hist -> offsets -> dst_scan ->
// scatter -> kq_f32 -> vproj(MFMA) -> U gemm -> VM gemm -> attend -> out.
//
// ws (4B words, 234.8 MB):
//  U 0..25.6M (hF alias: dead before U-gemm writes)
//  VM 25.6M..51.2M (qF alias: dead before VM-gemm writes)
//  kF 51.2M..54.4M | aggF 54.4M..57.6M (vF alias: dead before attend writes)
//  attF 57.6M | msgT 57.7M | WvT 57.8M | WaT 57.9M | int 58.0M..58.71M
// ---------------------------------------------------------------------------

#define N_NODES 50000
#define N_EDGES 500000
#define DIM 128
#define TT 8
#define RR 8
#define RSQRT_DK 0.08838834764831845f

#define CHUNK_GRID 399               // 399*128 = 51072 >= 50000 + 8*127
#define NODE_LIST_LEN (CHUNK_GRID * 128)
#define GRID_E ((N_EDGES + 255) / 256)   // 1954, also covers N
#define GEMM_ROWBLKS ((N_NODES + 127) / 128)  // 391

// word offsets (4B units); _Float16 index = 2*word
#define OFF_U 0
#define OFF_HF 0                   // alias: hF16 [n][128] (dead before U write)
#define OFF_VM 25600000
#define OFF_QF 25600000            // alias: qF16 (dead before VM write)
#define OFF_KF 51200000
#define OFF_AGGF 54400000
#define OFF_VF 54400000            // alias: vF16 (dead before attend writes agg)
#define OFF_ATTF 57600000          // 65,536 words each, 100k spacing
#define OFF_MSGT 57700000
#define OFF_WVT 57800000
#define OFF_WAT 57900000
#define OFF_INT 58000000           // int region, +701,104 -> 58,701,104 words
#define IO_NLIST 0                 // 51,072
#define IO_CNT_N 51072
#define IO_CUR_N 51080
#define IO_POFF_N 51088
#define IO_DCNT 51104              // 50,000
#define IO_DCUR 101104             // 50,000
#define IO_DOFF 151104             // 50,000
#define IO_DPR 201104              // 500,000 packed (src*8|rel) per CSR slot

typedef _Float16 half8 __attribute__((ext_vector_type(8)));
typedef _Float16 half4 __attribute__((ext_vector_type(4)));
typedef _Float16 half2t __attribute__((ext_vector_type(2)));
typedef float f32x4 __attribute__((ext_vector_type(4)));

__global__ void init_kernel(int* wsi) {
    int i = blockIdx.x * blockDim.x + threadIdx.x;
    if (i < NODE_LIST_LEN) wsi[IO_NLIST + i] = -1;
    if (i < 32) wsi[IO_CNT_N + i] = 0;
    if (i < 100000) wsi[IO_DCNT + i] = 0;  // dcnt + dcur contiguous
}

// attF straight [r][d][f]; msgT/WvT/WaT transposed to [.][f][d], all f16
__global__ void convert_kernel(const float* __restrict__ att,
                               const float* __restrict__ msg,
                               const float* __restrict__ Wv,
                               const float* __restrict__ Wa,
                               _Float16* __restrict__ attF,
                               _Float16* __restrict__ msgT,
                               _Float16* __restrict__ WvT,
                               _Float16* __restrict__ WaT) {
    int i = blockIdx.x * 256 + threadIdx.x;
    if (i >= RR * DIM * DIM) return;
    int td = i >> 14, d = (i >> 7) & 127, f = i & 127;
    int tr = (td << 14) + (f << 7) + d;
    attF[i] = (_Float16)att[i];
    msgT[tr] = (_Float16)msg[i];
    WvT[tr] = (_Float16)Wv[i];
    WaT[tr] = (_Float16)Wa[i];
}

__global__ void hconv_kernel(const float* __restrict__ h,
                             _Float16* __restrict__ hF) {
    int i = blockIdx.x * 256 + threadIdx.x;
    if (i < N_NODES * DIM / 4) {
        float4 v = ((const float4*)h)[i];
        half4 o;
        o[0] = (_Float16)v.x; o[1] = (_Float16)v.y;
        o[2] = (_Float16)v.z; o[3] = (_Float16)v.w;
        *(half4*)(hF + (size_t)i * 4) = o;
    }
}

__global__ void hist_kernel(const int* __restrict__ ntype,
                            const int* __restrict__ adj, int* wsi) {
    __shared__ int cn[TT];
    int tid = threadIdx.x;
    if (tid < TT) cn[tid] = 0;
    __syncthreads();
    int i = blockIdx.x * blockDim.x + tid;
    if (i < N_NODES) atomicAdd(&cn[ntype[i]], 1);
    if (i < N_EDGES) atomicAdd(&wsi[IO_DCNT + adj[N_EDGES + i]], 1);
    __syncthreads();
    if (tid < TT && cn[tid] > 0) atomicAdd(&wsi[IO_CNT_N + tid], cn[tid]);
}

__global__ void offsets_kernel(int* wsi) {
    int off = 0;
    for (int t = 0; t < TT; ++t) {
        wsi[IO_POFF_N + t] = off;
        off += ((wsi[IO_CNT_N + t] + 127) >> 7) << 7;  // pad to 128
    }
}

__global__ __launch_bounds__(256) void dst_scan_kernel(int* wsi) {
    __shared__ int part[256];
    int tid = threadIdx.x;
    const int CHUNK = (N_NODES + 255) / 256;
    int base = tid * CHUNK;
    int s = 0;
    for (int i = 0; i < CHUNK; ++i) {
        int idx = base + i;
        if (idx < N_NODES) s += wsi[IO_DCNT + idx];
    }
    part[tid] = s;
    __syncthreads();
    for (int off = 1; off < 256; off <<= 1) {
        int t = (tid >= off) ? part[tid - off] : 0;
        __syncthreads();
        part[tid] += t;
        __syncthreads();
    }
    int run = part[tid] - s;
    for (int i = 0; i < CHUNK; ++i) {
        int idx = base + i;
        if (idx < N_NODES) {
            int c = wsi[IO_DCNT + idx];
            wsi[IO_DOFF + idx] = run;
            run += c;
        }
    }
}

__global__ void scatter_kernel(const int* __restrict__ ntype,
                               const int* __restrict__ etype,
                               const int* __restrict__ adj, int* wsi) {
    __shared__ int cn[TT], bn[TT];
    int tid = threadIdx.x;
    if (tid < TT) cn[tid] = 0;
    __syncthreads();
    int i = blockIdx.x * blockDim.x + tid;
    int t = -1, rnk = 0;
    if (i < N_NODES) {
        t = ntype[i];
        rnk = atomicAdd(&cn[t], 1);
    }
    __syncthreads();
    if (tid < TT && cn[tid] > 0) bn[tid] = atomicAdd(&wsi[IO_CUR_N + tid], cn[tid]);
    __syncthreads();
    if (t >= 0)
        wsi[IO_NLIST + wsi[IO_POFF_N + t] + bn[t] + rnk] = i;
    if (i < N_EDGES) {
        int d = adj[N_EDGES + i];
        int pos = wsi[IO_DOFF + d] + atomicAdd(&wsi[IO_DCUR + d], 1);
        wsi[IO_DPR + pos] = (adj[i] << 3) | etype[i];  // packed src*8|rel
    }
}

// k,q: fp32 vector tile GEMM over 32-row slices of the 128-padded type
// chunks. Score path is argmax-sensitive: keep h and Wk/Wq in fp32 (R6
// post-mortem). f16 output rows. Bucket fill is a prefix -> nid[0]<0 means
// the whole slice is padding.
__global__ __launch_bounds__(256) void kq_f32_kernel(
    const float* __restrict__ h, const int* __restrict__ ntype,
    const float* __restrict__ Wk, const float* __restrict__ Wq,
    const int* __restrict__ nlist, _Float16* __restrict__ kout,
    _Float16* __restrict__ qout) {
    __shared__ float hl[32][DIM + 4];
    __shared__ int nid[32];
    int tid = threadIdx.x;
    int base = blockIdx.x * 32;
    if (tid < 32) nid[tid] = nlist[base + tid];
    __syncthreads();
    if (nid[0] < 0) return;
    int t = ntype[nid[0]];

    for (int r2 = 0; r2 < 32; r2 += 2) {
        int row = r2 + (tid >> 7);
        int col = tid & 127;
        int n = nid[row];
        if (n < 0) n = 0;
        hl[row][col] = h[(size_t)n * DIM + col];
    }
    __syncthreads();
    int te = tid >> 5, tc = tid & 31;

#pragma unroll
    for (int w = 0; w < 2; ++w) {
        const float* W = (w == 0 ? Wk : Wq) + (size_t)t * DIM * DIM;
        const float4* W4 = (const float4*)W;
        _Float16* O = (w == 0 ? kout : qout);
        float acc[4][4] = {};
        for (int i = 0; i < DIM; ++i) {
            float4 a = W4[i * 32 + tc];
#pragma unroll
            for (int j = 0; j < 4; ++j) {
                float hv = hl[te * 4 + j][i];
                acc[j][0] += hv * a.x;
                acc[j][1] += hv * a.y;
                acc[j][2] += hv * a.z;
                acc[j][3] += hv * a.w;
            }
        }
#pragma unroll
        for (int j = 0; j < 4; ++j) {
            int n = nid[te * 4 + j];
            if (n >= 0) {
                half4 o;
                o[0] = (_Float16)acc[j][0];
                o[1] = (_Float16)acc[j][1];
                o[2] = (_Float16)acc[j][2];
                o[3] = (_Float16)acc[j][3];
                *(half4*)(O + (size_t)n * DIM + tc * 4) = o;
            }
        }
    }
}

// v: 128-node type-uniform chunk MFMA GEMM (value path: f16-tolerant).
// MFMA 16x16x32 f16: A[m=l16][k=quad*8+j], B[k][n=l16], D col=l16 row=quad*4+rg
__global__ __launch_bounds__(256) void vproj_kernel(
    const _Float16* __restrict__ hF, const int* __restrict__ ntype,
    const _Float16* __restrict__ WvT, const int* __restrict__ nlist,
    _Float16* __restrict__ vout) {
    __shared__ int nid[128];
    int tid = threadIdx.x;
    if (tid < 128) nid[tid] = nlist[blockIdx.x * 128 + tid];
    __syncthreads();
    if (nid[0] < 0) return;
    int t = ntype[nid[0]];
    int wv = tid >> 6, lane = tid & 63, l16 = lane & 15, quad = lane >> 4;
    int r0 = wv * 32;
    int nA[2];
#pragma unroll
    for (int m = 0; m < 2; ++m) nA[m] = nid[r0 + m * 16 + l16];
    const _Float16* B = WvT + (t << 14);
    f32x4 acc[2][8];
#pragma unroll
    for (int m = 0; m < 2; ++m)
#pragma unroll
        for (int c = 0; c < 8; ++c) acc[m][c] = (f32x4){0.f, 0.f, 0.f, 0.f};
    for (int kk = 0; kk < 4; ++kk) {
        int kb = kk * 32 + quad * 8;
        half8 a[2];
#pragma unroll
        for (int m = 0; m < 2; ++m)
            a[m] = (nA[m] >= 0)
                       ? *(const half8*)(hF + (size_t)nA[m] * DIM + kb)
                       : (half8){0, 0, 0, 0, 0, 0, 0, 0};
#pragma unroll
        for (int c = 0; c < 8; ++c) {
            half8 b = *(const half8*)(B + (c * 16 + l16) * DIM + kb);
#pragma unroll
            for (int m = 0; m < 2; ++m)
                acc[m][c] = __builtin_amdgcn_mfma_f32_16x16x32_f16(
                    a[m], b, acc[m][c], 0, 0, 0);
        }
    }
#pragma unroll
    for (int m = 0; m < 2; ++m)
#pragma unroll
        for (int c = 0; c < 8; ++c)
#pragma unroll
            for (int rg = 0; rg < 4; ++rg) {
                int node = nid[r0 + m * 16 + quad * 4 + rg];
                if (node >= 0)
                    vout[(size_t)node * DIM + c * 16 + l16] =
                        (_Float16)acc[m][c][rg];
            }
}

// Dense MFMA GEMM: Out[n, rel, col] = sum_k A[n,k] * B[rel, col, k]
__global__ __launch_bounds__(256) void nr_gemm_kernel(
    const _Float16* __restrict__ A, const _Float16* __restrict__ B,
    _Float16* __restrict__ Of) {
    int rel = blockIdx.y;
    int tid = threadIdx.x;
    int wv = tid >> 6, lane = tid & 63;
    int l16 = lane & 15, quad = lane >> 4;
    int row0 = blockIdx.x * 128 + wv * 32;
    const _Float16* Bbase = B + rel * DIM * DIM;
    f32x4 acc[2][8];
#pragma unroll
    for (int m = 0; m < 2; ++m)
#pragma unroll
        for (int c = 0; c < 8; ++c) acc[m][c] = (f32x4){0.f, 0.f, 0.f, 0.f};

    for (int kk = 0; kk < 4; ++kk) {
        int kb = kk * 32 + quad * 8;
        half8 a[2];
#pragma unroll
        for (int m = 0; m < 2; ++m) {
            int node = row0 + m * 16 + l16;
            if (node < N_NODES)
                a[m] = *(const half8*)(A + (size_t)node * DIM + kb);
            else
                a[m] = (half8){0, 0, 0, 0, 0, 0, 0, 0};
        }
#pragma unroll
        for (int c = 0; c < 8; ++c) {
            half8 b = *(const half8*)(Bbase + (c * 16 + l16) * DIM + kb);
#pragma unroll
            for (int m = 0; m < 2; ++m)
                acc[m][c] = __builtin_amdgcn_mfma_f32_16x16x32_f16(
                    a[m], b, acc[m][c], 0, 0, 0);
        }
    }
#pragma unroll
    for (int m = 0; m < 2; ++m)
#pragma unroll
        for (int c = 0; c < 8; ++c)
#pragma unroll
            for (int rg = 0; rg < 4; ++rg) {
                int node = row0 + m * 16 + quad * 4 + rg;
                if (node < N_NODES)
                    Of[((size_t)node * RR + rel) * DIM + c * 16 + l16] =
                        (_Float16)acc[m][c][rg];
            }
}

// Fused score+softmax+aggregate: one wave per dst node. Per-edge score via
// 64-lane dot + xor-reduce; per-(dst,rel) max/sum in registers; per-edge
// s/ex + packed(src,rel) parked in lane (j&63)'s regs (192 edges; beyond
// that recompute — Poisson(10) degree makes overflow negligible).
__global__ __launch_bounds__(256) void attend_kernel(
    const _Float16* __restrict__ kF, const _Float16* __restrict__ UF,
    const _Float16* __restrict__ VMF, const float* __restrict__ pri,
    const int* __restrict__ dpr, const int* __restrict__ doff,
    const int* __restrict__ dcnt, _Float16* __restrict__ aggF) {
    int wv = threadIdx.x >> 6, lane = threadIdx.x & 63;
    int dst = blockIdx.x * 4 + wv;
    if (dst >= N_NODES) return;
    int beg = doff[dst], cnt = dcnt[dst];
    float prv[RR], m[RR], sum[RR];
#pragma unroll
    for (int r = 0; r < RR; ++r) {
        prv[r] = pri[r] * RSQRT_DK;
        m[r] = -1e30f;
        sum[r] = 0.f;
    }
    float sreg[3];
    int preg[3];
    // phase 1: scores + per-rel max
    for (int j = 0; j < cnt; ++j) {
        int pr = dpr[beg + j];
        int src = pr >> 3, rel = pr & 7;
        half2t kv = *(const half2t*)(kF + (size_t)src * DIM + lane * 2);
        half2t uv =
            *(const half2t*)(UF + ((size_t)dst * RR + rel) * DIM + lane * 2);
        float s = (float)kv[0] * (float)uv[0] + (float)kv[1] * (float)uv[1];
#pragma unroll
        for (int o = 32; o > 0; o >>= 1) s += __shfl_xor(s, o, 64);
        s *= prv[rel];
        if (s > m[rel]) m[rel] = s;
        int slot = j >> 6;
        if (slot < 3 && lane == (j & 63)) {
            sreg[slot] = s;
            preg[slot] = pr;
        }
    }
    // phase 2: per-rel sums; park ex back in the slot
    for (int j = 0; j < cnt; ++j) {
        float s;
        int pr;
        if (j < 192) {
            s = __shfl(sreg[j >> 6], j & 63, 64);
            pr = __shfl(preg[j >> 6], j & 63, 64);
        } else {
            pr = dpr[beg + j];
            int src = pr >> 3, rel = pr & 7;
            half2t kv = *(const half2t*)(kF + (size_t)src * DIM + lane * 2);
            half2t uv =
                *(const half2t*)(UF + ((size_t)dst * RR + rel) * DIM + lane * 2);
            s = (float)kv[0] * (float)uv[0] + (float)kv[1] * (float)uv[1];
#pragma unroll
            for (int o = 32; o > 0; o >>= 1) s += __shfl_xor(s, o, 64);
            s *= prv[rel];
        }
        int rel = pr & 7;
        float ex = __expf(s - m[rel]);
        sum[rel] += ex;
        int slot = j >> 6;
        if (slot < 3 && lane == (j & 63)) sreg[slot] = ex;
    }
    // phase 3: alpha-weighted VM gather
    float a0 = 0.f, a1 = 0.f;
    for (int j = 0; j < cnt; ++j) {
        float ex;
        int pr;
        if (j < 192) {
            ex = __shfl(sreg[j >> 6], j & 63, 64);
            pr = __shfl(preg[j >> 6], j & 63, 64);
        } else {
            pr = dpr[beg + j];
            int src = pr >> 3, rel = pr & 7;
            half2t kv = *(const half2t*)(kF + (size_t)src * DIM + lane * 2);
            half2t uv =
                *(const half2t*)(UF + ((size_t)dst * RR + rel) * DIM + lane * 2);
            float s = (float)kv[0] * (float)uv[0] + (float)kv[1] * (float)uv[1];
#pragma unroll
            for (int o = 32; o > 0; o >>= 1) s += __shfl_xor(s, o, 64);
            s *= prv[rel];
            ex = __expf(s - m[rel]);
        }
        int rel = pr & 7, src = pr >> 3;
        float alpha = ex / sum[rel];
        half2t v =
            *(const half2t*)(VMF + ((size_t)src * RR + rel) * DIM + lane * 2);
        a0 += alpha * (float)v[0];
        a1 += alpha * (float)v[1];
    }
    half2t o;
    o[0] = (_Float16)a0;
    o[1] = (_Float16)a1;
    *(half2t*)(aggF + (size_t)dst * DIM + lane * 2) = o;
}

// out: 128-node type-uniform chunk MFMA GEMM, fp32 stores with sigmoid gate
__global__ __launch_bounds__(256) void out_kernel(
    const _Float16* __restrict__ aggF, const int* __restrict__ ntype,
    const _Float16* __restrict__ WaT, const float* __restrict__ skip,
    const int* __restrict__ nlist, float* __restrict__ out) {
    __shared__ int nid[128];
    int tid = threadIdx.x;
    if (tid < 128) nid[tid] = nlist[blockIdx.x * 128 + tid];
    __syncthreads();
    if (nid[0] < 0) return;
    int t = ntype[nid[0]];
    float sig = 1.f / (1.f + __expf(-skip[t]));
    int wv = tid >> 6, lane = tid & 63, l16 = lane & 15, quad = lane >> 4;
    int r0 = wv * 32;
    int nA[2];
#pragma unroll
    for (int m = 0; m < 2; ++m) nA[m] = nid[r0 + m * 16 + l16];
    const _Float16* B = WaT + (t << 14);
    f32x4 acc[2][8];
#pragma unroll
    for (int m = 0; m < 2; ++m)
#pragma unroll
        for (int c = 0; c < 8; ++c) acc[m][c] = (f32x4){0.f, 0.f, 0.f, 0.f};
    for (int kk = 0; kk < 4; ++kk) {
        int kb = kk * 32 + quad * 8;
        half8 a[2];
#pragma unroll
        for (int m = 0; m < 2; ++m)
            a[m] = (nA[m] >= 0)
                       ? *(const half8*)(aggF + (size_t)nA[m] * DIM + kb)
                       : (half8){0, 0, 0, 0, 0, 0, 0, 0};
#pragma unroll
        for (int c = 0; c < 8; ++c) {
            half8 b = *(const half8*)(B + (c * 16 + l16) * DIM + kb);
#pragma unroll
            for (int m = 0; m < 2; ++m)
                acc[m][c] = __builtin_amdgcn_mfma_f32_16x16x32_f16(
                    a[m], b, acc[m][c], 0, 0, 0);
        }
    }
#pragma unroll
    for (int m = 0; m < 2; ++m)
#pragma unroll
        for (int c = 0; c < 8; ++c)
#pragma unroll
            for (int rg = 0; rg < 4; ++rg) {
                int node = nid[r0 + m * 16 + quad * 4 + rg];
                if (node >= 0)
                    out[(size_t)node * DIM + c * 16 + l16] =
                        acc[m][c][rg] * sig;
            }
}

extern "C" void kernel_launch(void* const* d_in, const int* in_sizes, int n_in,
                              void* d_out, int out_size, void* d_ws,
                              size_t ws_size, hipStream_t stream) {
    const float* h = (const float*)d_in[0];
    const int* adj = (const int*)d_in[1];
    const int* etype = (const int*)d_in[2];
    const int* ntype = (const int*)d_in[3];
    const float* Wk = (const float*)d_in[6];
    const float* Wq = (const float*)d_in[7];
    const float* Wv = (const float*)d_in[8];
    const float* Wa = (const float*)d_in[9];
    const float* pri = (const float*)d_in[10];
    const float* att = (const float*)d_in[11];
    const float* msg = (const float*)d_in[12];
    const float* skip = (const float*)d_in[13];
    float* out = (float*)d_out;

    int* wsi = (int*)d_ws + OFF_INT;
    _Float16* wsh = (_Float16*)d_ws;
    _Float16* UF = wsh + (size_t)OFF_U * 2;
    _Float16* hF = wsh + (size_t)OFF_HF * 2;
    _Float16* VMF = wsh + (size_t)OFF_VM * 2;
    _Float16* qF = wsh + (size_t)OFF_QF * 2;
    _Float16* kF = wsh + (size_t)OFF_KF * 2;
    _Float16* aggF = wsh + (size_t)OFF_AGGF * 2;
    _Float16* vF = wsh + (size_t)OFF_VF * 2;
    _Float16* attF = wsh + (size_t)OFF_ATTF * 2;
    _Float16* msgT = wsh + (size_t)OFF_MSGT * 2;
    _Float16* WvT = wsh + (size_t)OFF_WVT * 2;
    _Float16* WaT = wsh + (size_t)OFF_WAT * 2;

    init_kernel<<<(100000 + 255) / 256, 256, 0, stream>>>(wsi);
    convert_kernel<<<(RR * DIM * DIM + 255) / 256, 256, 0, stream>>>(
        att, msg, Wv, Wa, attF, msgT, WvT, WaT);
    hconv_kernel<<<(N_NODES * DIM / 4 + 255) / 256, 256, 0, stream>>>(h, hF);
    hist_kernel<<<GRID_E, 256, 0, stream>>>(ntype, adj, wsi);
    offsets_kernel<<<1, 1, 0, stream>>>(wsi);
    dst_scan_kernel<<<1, 256, 0, stream>>>(wsi);
    scatter_kernel<<<GRID_E, 256, 0, stream>>>(ntype, etype, adj, wsi);
    kq_f32_kernel<<<CHUNK_GRID * 4, 256, 0, stream>>>(h, ntype, Wk, Wq,
                                                      wsi + IO_NLIST, kF, qF);
    vproj_kernel<<<CHUNK_GRID, 256, 0, stream>>>(hF, ntype, WvT,
                                                 wsi + IO_NLIST, vF);
    {
        dim3 g(GEMM_ROWBLKS, RR);
        nr_gemm_kernel<<<g, 256, 0, stream>>>(qF, attF, UF);   // U = q @ att^T
        nr_gemm_kernel<<<g, 256, 0, stream>>>(vF, msgT, VMF);  // VM = v @ msg
    }
    attend_kernel<<<(N_NODES + 3) / 4, 256, 0, stream>>>(
        kF, UF, VMF, pri, wsi + IO_DPR, wsi + IO_DOFF, wsi + IO_DCNT, aggF);
    out_kernel<<<CHUNK_GRID, 256, 0, stream>>>(aggF, ntype, WaT, skip,
                                               wsi + IO_NLIST, out);
}

// Round 9
// 566.462 us; speedup vs baseline: 10.0807x; 1.1977x over previous
//
#include <hip/hip_runtime.h>
#include <math.h>

// ---------------------------------------------------------------------------
// HGT layer slice. R9: R8 attend with the padding-edge bug fixed.
//
// R8 post-mortem: invalid group-edges (cnt%4 != 0) parked s=-3e38/pr=0; for
// dsts with no real rel-0 edge m[0] stayed -3e38, so exp(s-m)=exp(0)=1 ->
// spurious alpha*VM[0,0] row injected into agg (absmax 21504). Fix: mask
// ex=0 for invalid edges in phases 2/3 (parked ex carries the mask).
//
// attend v2: 16 lanes/edge, 4 edges in flight per wave; lane l owns softmax
// state (m,sum) for rel l&7 in scalar regs (lookup = 1 shfl, update = masked
// max/add); park slot/lane indices wave-uniform -> no dynamic indexing, no
// scratch spills (R7: VGPR 36 + scratch = 183 us).
//
// Pipeline: init -> convert -> hconv -> hist -> offsets -> dst_scan ->
// scatter -> kq_f32 -> vproj(MFMA) -> U gemm(pri*rsqrt_dk folded) ->
// VM gemm -> attend -> out(MFMA).  ws layout identical to R7 (234.8 MB).
// ---------------------------------------------------------------------------

#define N_NODES 50000
#define N_EDGES 500000
#define DIM 128
#define TT 8
#define RR 8
#define RSQRT_DK 0.08838834764831845f

#define CHUNK_GRID 399               // 399*128 = 51072 >= 50000 + 8*127
#define NODE_LIST_LEN (CHUNK_GRID * 128)
#define GRID_E ((N_EDGES + 255) / 256)   // 1954, also covers N
#define GEMM_ROWBLKS ((N_NODES + 127) / 128)  // 391

// word offsets (4B units); _Float16 index = 2*word
#define OFF_U 0
#define OFF_HF 0                   // alias: hF16 [n][128] (dead before U write)
#define OFF_VM 25600000
#define OFF_QF 25600000            // alias: qF16 (dead before VM write)
#define OFF_KF 51200000
#define OFF_AGGF 54400000
#define OFF_VF 54400000            // alias: vF16 (dead before attend writes agg)
#define OFF_ATTF 57600000          // 65,536 words each, 100k spacing
#define OFF_MSGT 57700000
#define OFF_WVT 57800000
#define OFF_WAT 57900000
#define OFF_INT 58000000           // int region, +701,104 -> 58,701,104 words
#define IO_NLIST 0                 // 51,072
#define IO_CNT_N 51072
#define IO_CUR_N 51080
#define IO_POFF_N 51088
#define IO_DCNT 51104              // 50,000
#define IO_DCUR 101104             // 50,000
#define IO_DOFF 151104             // 50,000
#define IO_DPR 201104              // 500,000 packed (src*8|rel) per CSR slot

typedef _Float16 half8 __attribute__((ext_vector_type(8)));
typedef _Float16 half4 __attribute__((ext_vector_type(4)));
typedef float f32x4 __attribute__((ext_vector_type(4)));

__global__ void init_kernel(int* wsi) {
    int i = blockIdx.x * blockDim.x + threadIdx.x;
    if (i < NODE_LIST_LEN) wsi[IO_NLIST + i] = -1;
    if (i < 32) wsi[IO_CNT_N + i] = 0;
    if (i < 100000) wsi[IO_DCNT + i] = 0;  // dcnt + dcur contiguous
}

// attF straight [r][d][f]; msgT/WvT/WaT transposed to [.][f][d], all f16
__global__ void convert_kernel(const float* __restrict__ att,
                               const float* __restrict__ msg,
                               const float* __restrict__ Wv,
                               const float* __restrict__ Wa,
                               _Float16* __restrict__ attF,
                               _Float16* __restrict__ msgT,
                               _Float16* __restrict__ WvT,
                               _Float16* __restrict__ WaT) {
    int i = blockIdx.x * 256 + threadIdx.x;
    if (i >= RR * DIM * DIM) return;
    int td = i >> 14, d = (i >> 7) & 127, f = i & 127;
    int tr = (td << 14) + (f << 7) + d;
    attF[i] = (_Float16)att[i];
    msgT[tr] = (_Float16)msg[i];
    WvT[tr] = (_Float16)Wv[i];
    WaT[tr] = (_Float16)Wa[i];
}

__global__ void hconv_kernel(const float* __restrict__ h,
                             _Float16* __restrict__ hF) {
    int i = blockIdx.x * 256 + threadIdx.x;
    if (i < N_NODES * DIM / 4) {
        float4 v = ((const float4*)h)[i];
        half4 o;
        o[0] = (_Float16)v.x; o[1] = (_Float16)v.y;
        o[2] = (_Float16)v.z; o[3] = (_Float16)v.w;
        *(half4*)(hF + (size_t)i * 4) = o;
    }
}

__global__ void hist_kernel(const int* __restrict__ ntype,
                            const int* __restrict__ adj, int* wsi) {
    __shared__ int cn[TT];
    int tid = threadIdx.x;
    if (tid < TT) cn[tid] = 0;
    __syncthreads();
    int i = blockIdx.x * blockDim.x + tid;
    if (i < N_NODES) atomicAdd(&cn[ntype[i]], 1);
    if (i < N_EDGES) atomicAdd(&wsi[IO_DCNT + adj[N_EDGES + i]], 1);
    __syncthreads();
    if (tid < TT && cn[tid] > 0) atomicAdd(&wsi[IO_CNT_N + tid], cn[tid]);
}

__global__ void offsets_kernel(int* wsi) {
    int off = 0;
    for (int t = 0; t < TT; ++t) {
        wsi[IO_POFF_N + t] = off;
        off += ((wsi[IO_CNT_N + t] + 127) >> 7) << 7;  // pad to 128
    }
}

__global__ __launch_bounds__(256) void dst_scan_kernel(int* wsi) {
    __shared__ int part[256];
    int tid = threadIdx.x;
    const int CHUNK = (N_NODES + 255) / 256;
    int base = tid * CHUNK;
    int s = 0;
    for (int i = 0; i < CHUNK; ++i) {
        int idx = base + i;
        if (idx < N_NODES) s += wsi[IO_DCNT + idx];
    }
    part[tid] = s;
    __syncthreads();
    for (int off = 1; off < 256; off <<= 1) {
        int t = (tid >= off) ? part[tid - off] : 0;
        __syncthreads();
        part[tid] += t;
        __syncthreads();
    }
    int run = part[tid] - s;
    for (int i = 0; i < CHUNK; ++i) {
        int idx = base + i;
        if (idx < N_NODES) {
            int c = wsi[IO_DCNT + idx];
            wsi[IO_DOFF + idx] = run;
            run += c;
        }
    }
}

__global__ void scatter_kernel(const int* __restrict__ ntype,
                               const int* __restrict__ etype,
                               const int* __restrict__ adj, int* wsi) {
    __shared__ int cn[TT], bn[TT];
    int tid = threadIdx.x;
    if (tid < TT) cn[tid] = 0;
    __syncthreads();
    int i = blockIdx.x * blockDim.x + tid;
    int t = -1, rnk = 0;
    if (i < N_NODES) {
        t = ntype[i];
        rnk = atomicAdd(&cn[t], 1);
    }
    __syncthreads();
    if (tid < TT && cn[tid] > 0) bn[tid] = atomicAdd(&wsi[IO_CUR_N + tid], cn[tid]);
    __syncthreads();
    if (t >= 0)
        wsi[IO_NLIST + wsi[IO_POFF_N + t] + bn[t] + rnk] = i;
    if (i < N_EDGES) {
        int d = adj[N_EDGES + i];
        int pos = wsi[IO_DOFF + d] + atomicAdd(&wsi[IO_DCUR + d], 1);
        wsi[IO_DPR + pos] = (adj[i] << 3) | etype[i];  // packed src*8|rel
    }
}

// k,q: fp32 vector tile GEMM (score path is argmax-sensitive; R6 post-mortem)
__global__ __launch_bounds__(256) void kq_f32_kernel(
    const float* __restrict__ h, const int* __restrict__ ntype,
    const float* __restrict__ Wk, const float* __restrict__ Wq,
    const int* __restrict__ nlist, _Float16* __restrict__ kout,
    _Float16* __restrict__ qout) {
    __shared__ float hl[32][DIM + 4];
    __shared__ int nid[32];
    int tid = threadIdx.x;
    int base = blockIdx.x * 32;
    if (tid < 32) nid[tid] = nlist[base + tid];
    __syncthreads();
    if (nid[0] < 0) return;
    int t = ntype[nid[0]];

    for (int r2 = 0; r2 < 32; r2 += 2) {
        int row = r2 + (tid >> 7);
        int col = tid & 127;
        int n = nid[row];
        if (n < 0) n = 0;
        hl[row][col] = h[(size_t)n * DIM + col];
    }
    __syncthreads();
    int te = tid >> 5, tc = tid & 31;

#pragma unroll
    for (int w = 0; w < 2; ++w) {
        const float* W = (w == 0 ? Wk : Wq) + (size_t)t * DIM * DIM;
        const float4* W4 = (const float4*)W;
        _Float16* O = (w == 0 ? kout : qout);
        float acc[4][4] = {};
        for (int i = 0; i < DIM; ++i) {
            float4 a = W4[i * 32 + tc];
#pragma unroll
            for (int j = 0; j < 4; ++j) {
                float hv = hl[te * 4 + j][i];
                acc[j][0] += hv * a.x;
                acc[j][1] += hv * a.y;
                acc[j][2] += hv * a.z;
                acc[j][3] += hv * a.w;
            }
        }
#pragma unroll
        for (int j = 0; j < 4; ++j) {
            int n = nid[te * 4 + j];
            if (n >= 0) {
                half4 o;
                o[0] = (_Float16)acc[j][0];
                o[1] = (_Float16)acc[j][1];
                o[2] = (_Float16)acc[j][2];
                o[3] = (_Float16)acc[j][3];
                *(half4*)(O + (size_t)n * DIM + tc * 4) = o;
            }
        }
    }
}

// v: 128-node type-uniform chunk MFMA GEMM (value path: f16-tolerant)
__global__ __launch_bounds__(256) void vproj_kernel(
    const _Float16* __restrict__ hF, const int* __restrict__ ntype,
    const _Float16* __restrict__ WvT, const int* __restrict__ nlist,
    _Float16* __restrict__ vout) {
    __shared__ int nid[128];
    int tid = threadIdx.x;
    if (tid < 128) nid[tid] = nlist[blockIdx.x * 128 + tid];
    __syncthreads();
    if (nid[0] < 0) return;
    int t = ntype[nid[0]];
    int wv = tid >> 6, lane = tid & 63, l16 = lane & 15, quad = lane >> 4;
    int r0 = wv * 32;
    int nA[2];
#pragma unroll
    for (int m = 0; m < 2; ++m) nA[m] = nid[r0 + m * 16 + l16];
    const _Float16* B = WvT + (t << 14);
    f32x4 acc[2][8];
#pragma unroll
    for (int m = 0; m < 2; ++m)
#pragma unroll
        for (int c = 0; c < 8; ++c) acc[m][c] = (f32x4){0.f, 0.f, 0.f, 0.f};
    for (int kk = 0; kk < 4; ++kk) {
        int kb = kk * 32 + quad * 8;
        half8 a[2];
#pragma unroll
        for (int m = 0; m < 2; ++m)
            a[m] = (nA[m] >= 0)
                       ? *(const half8*)(hF + (size_t)nA[m] * DIM + kb)
                       : (half8){0, 0, 0, 0, 0, 0, 0, 0};
#pragma unroll
        for (int c = 0; c < 8; ++c) {
            half8 b = *(const half8*)(B + (c * 16 + l16) * DIM + kb);
#pragma unroll
            for (int m = 0; m < 2; ++m)
                acc[m][c] = __builtin_amdgcn_mfma_f32_16x16x32_f16(
                    a[m], b, acc[m][c], 0, 0, 0);
        }
    }
#pragma unroll
    for (int m = 0; m < 2; ++m)
#pragma unroll
        for (int c = 0; c < 8; ++c)
#pragma unroll
            for (int rg = 0; rg < 4; ++rg) {
                int node = nid[r0 + m * 16 + quad * 4 + rg];
                if (node >= 0)
                    vout[(size_t)node * DIM + c * 16 + l16] =
                        (_Float16)acc[m][c][rg];
            }
}

// Dense MFMA GEMM: Out[n, rel, col] = scale_r * sum_k A[n,k] * B[rel, col, k]
__global__ __launch_bounds__(256) void nr_gemm_kernel(
    const _Float16* __restrict__ A, const _Float16* __restrict__ B,
    _Float16* __restrict__ Of, const float* __restrict__ pri, int doscale) {
    int rel = blockIdx.y;
    int tid = threadIdx.x;
    int wv = tid >> 6, lane = tid & 63;
    int l16 = lane & 15, quad = lane >> 4;
    int row0 = blockIdx.x * 128 + wv * 32;
    const _Float16* Bbase = B + rel * DIM * DIM;
    float scale = doscale ? pri[rel] * RSQRT_DK : 1.0f;
    f32x4 acc[2][8];
#pragma unroll
    for (int m = 0; m < 2; ++m)
#pragma unroll
        for (int c = 0; c < 8; ++c) acc[m][c] = (f32x4){0.f, 0.f, 0.f, 0.f};

    for (int kk = 0; kk < 4; ++kk) {
        int kb = kk * 32 + quad * 8;
        half8 a[2];
#pragma unroll
        for (int m = 0; m < 2; ++m) {
            int node = row0 + m * 16 + l16;
            if (node < N_NODES)
                a[m] = *(const half8*)(A + (size_t)node * DIM + kb);
            else
                a[m] = (half8){0, 0, 0, 0, 0, 0, 0, 0};
        }
#pragma unroll
        for (int c = 0; c < 8; ++c) {
            half8 b = *(const half8*)(Bbase + (c * 16 + l16) * DIM + kb);
#pragma unroll
            for (int m = 0; m < 2; ++m)
                acc[m][c] = __builtin_amdgcn_mfma_f32_16x16x32_f16(
                    a[m], b, acc[m][c], 0, 0, 0);
        }
    }
#pragma unroll
    for (int m = 0; m < 2; ++m)
#pragma unroll
        for (int c = 0; c < 8; ++c)
#pragma unroll
            for (int rg = 0; rg < 4; ++rg) {
                int node = row0 + m * 16 + quad * 4 + rg;
                if (node < N_NODES)
                    Of[((size_t)node * RR + rel) * DIM + c * 16 + l16] =
                        (_Float16)(acc[m][c][rg] * scale);
            }
}

// ---------------------------------------------------------------------------
// attend v2.1: fused score+softmax+aggregate, one wave per dst.
// group g = lane>>4 handles edge j0+g; 16 lanes per edge (half8 = 128 elems).
// Lane l owns (m,sum) for rel l&7; parking wave-uniform (slot j0>>6, lane
// (j0>>2)&15). Invalid padding edges (j>=cnt) carry ex=0 through phases 2/3
// (R8 bug: they produced exp(0)=1 when their rel had no real edges).
// ---------------------------------------------------------------------------
__global__ __launch_bounds__(256) void attend_kernel(
    const _Float16* __restrict__ kF, const _Float16* __restrict__ UF,
    const _Float16* __restrict__ VMF, const int* __restrict__ dpr,
    const int* __restrict__ doff, const int* __restrict__ dcnt,
    _Float16* __restrict__ aggF) {
    int wv = threadIdx.x >> 6, lane = threadIdx.x & 63;
    int dst = blockIdx.x * 4 + wv;
    if (dst >= N_NODES) return;
    int l16 = lane & 15, g = lane >> 4, l8 = lane & 7;
    int beg = doff[dst], cnt = dcnt[dst];

    float m_own = -3e38f, sum_own = 0.f;
    float s0 = 0.f, s1 = 0.f, s2 = 0.f;
    int p0 = 0, p1 = 0, p2 = 0;

    // phase 1: scores, park (s, pr), lane-owned per-rel max
    for (int j0 = 0; j0 < cnt; j0 += 4) {
        int j = j0 + g;
        bool valid = j < cnt;
        int pr = valid ? dpr[beg + j] : 0;
        int src = pr >> 3, rel = pr & 7;
        half8 kv = *(const half8*)(kF + (size_t)src * DIM + l16 * 8);
        half8 uv =
            *(const half8*)(UF + ((size_t)dst * RR + rel) * DIM + l16 * 8);
        float s = 0.f;
#pragma unroll
        for (int i = 0; i < 8; ++i) s += (float)kv[i] * (float)uv[i];
        s += __shfl_xor(s, 1, 16);
        s += __shfl_xor(s, 2, 16);
        s += __shfl_xor(s, 4, 16);
        s += __shfl_xor(s, 8, 16);
        if (!valid) s = -3e38f;
        int slot = j0 >> 6;            // wave-uniform
        int idx = (j0 >> 2) & 15;      // wave-uniform
        if (l16 == idx) {
            if (slot == 0) { s0 = s; p0 = pr; }
            else if (slot == 1) { s1 = s; p1 = pr; }
            else if (slot == 2) { s2 = s; p2 = pr; }
        }
        if (valid && l8 == rel && s > m_own) m_own = s;
    }
    // merge per-rel max across the 4 groups
    m_own = fmaxf(m_own, __shfl_xor(m_own, 16, 64));
    m_own = fmaxf(m_own, __shfl_xor(m_own, 32, 64));

    // phase 2: ex = valid ? exp(s - m[rel]) : 0; park ex; lane-owned sum
    for (int j0 = 0; j0 < cnt; j0 += 4) {
        int j = j0 + g;
        bool valid = j < cnt;
        int slot = j0 >> 6;
        int idx = (j0 >> 2) & 15;
        float s;
        int pr;
        if (slot < 3) {
            float sv = (slot == 0) ? s0 : (slot == 1) ? s1 : s2;
            int pv = (slot == 0) ? p0 : (slot == 1) ? p1 : p2;
            s = __shfl(sv, idx, 16);
            pr = __shfl(pv, idx, 16);
        } else {  // overflow fallback: recompute (cnt>192 ~ never at deg~10)
            pr = valid ? dpr[beg + j] : 0;
            int src = pr >> 3, rel = pr & 7;
            half8 kv = *(const half8*)(kF + (size_t)src * DIM + l16 * 8);
            half8 uv =
                *(const half8*)(UF + ((size_t)dst * RR + rel) * DIM + l16 * 8);
            s = 0.f;
#pragma unroll
            for (int i = 0; i < 8; ++i) s += (float)kv[i] * (float)uv[i];
            s += __shfl_xor(s, 1, 16);
            s += __shfl_xor(s, 2, 16);
            s += __shfl_xor(s, 4, 16);
            s += __shfl_xor(s, 8, 16);
        }
        int rel = pr & 7;
        float mr = __shfl(m_own, rel, 8);
        float ex = valid ? __expf(s - mr) : 0.f;  // R8 bug fix: mask padding
        if (l16 == idx) {
            if (slot == 0) s0 = ex;
            else if (slot == 1) s1 = ex;
            else if (slot == 2) s2 = ex;
        }
        if (l8 == rel) sum_own += ex;
    }
    // merge per-rel sums; invert once
    sum_own += __shfl_xor(sum_own, 16, 64);
    sum_own += __shfl_xor(sum_own, 32, 64);
    float inv_own = (sum_own > 0.f) ? 1.f / sum_own : 0.f;

    // phase 3: acc += alpha * VM[src, rel]  (parked ex is already 0 for pads)
    float acc[8] = {0.f, 0.f, 0.f, 0.f, 0.f, 0.f, 0.f, 0.f};
    for (int j0 = 0; j0 < cnt; j0 += 4) {
        int j = j0 + g;
        bool valid = j < cnt;
        int slot = j0 >> 6;
        int idx = (j0 >> 2) & 15;
        float ex;
        int pr;
        if (slot < 3) {
            float sv = (slot == 0) ? s0 : (slot == 1) ? s1 : s2;
            int pv = (slot == 0) ? p0 : (slot == 1) ? p1 : p2;
            ex = __shfl(sv, idx, 16);
            pr = __shfl(pv, idx, 16);
        } else {
            pr = valid ? dpr[beg + j] : 0;
            int src = pr >> 3, rel = pr & 7;
            half8 kv = *(const half8*)(kF + (size_t)src * DIM + l16 * 8);
            half8 uv =
                *(const half8*)(UF + ((size_t)dst * RR + rel) * DIM + l16 * 8);
            float s = 0.f;
#pragma unroll
            for (int i = 0; i < 8; ++i) s += (float)kv[i] * (float)uv[i];
            s += __shfl_xor(s, 1, 16);
            s += __shfl_xor(s, 2, 16);
            s += __shfl_xor(s, 4, 16);
            s += __shfl_xor(s, 8, 16);
            float mr = __shfl(m_own, (pr & 7), 8);
            ex = valid ? __expf(s - mr) : 0.f;  // R8 bug fix: mask padding
        }
        int rel = pr & 7, src = pr >> 3;
        float alpha = ex * __shfl(inv_own, rel, 8);
        half8 v =
            *(const half8*)(VMF + ((size_t)src * RR + rel) * DIM + l16 * 8);
#pragma unroll
        for (int i = 0; i < 8; ++i) acc[i] += alpha * (float)v[i];
    }
    // merge acc across the 4 groups (each covers the full 128 dims)
#pragma unroll
    for (int i = 0; i < 8; ++i) {
        acc[i] += __shfl_xor(acc[i], 16, 64);
        acc[i] += __shfl_xor(acc[i], 32, 64);
    }
    if (g == 0) {
        half8 o;
#pragma unroll
        for (int i = 0; i < 8; ++i) o[i] = (_Float16)acc[i];
        *(half8*)(aggF + (size_t)dst * DIM + l16 * 8) = o;
    }
}

// out: 128-node type-uniform chunk MFMA GEMM, fp32 stores with sigmoid gate
__global__ __launch_bounds__(256) void out_kernel(
    const _Float16* __restrict__ aggF, const int* __restrict__ ntype,
    const _Float16* __restrict__ WaT, const float* __restrict__ skip,
    const int* __restrict__ nlist, float* __restrict__ out) {
    __shared__ int nid[128];
    int tid = threadIdx.x;
    if (tid < 128) nid[tid] = nlist[blockIdx.x * 128 + tid];
    __syncthreads();
    if (nid[0] < 0) return;
    int t = ntype[nid[0]];
    float sig = 1.f / (1.f + __expf(-skip[t]));
    int wv = tid >> 6, lane = tid & 63, l16 = lane & 15, quad = lane >> 4;
    int r0 = wv * 32;
    int nA[2];
#pragma unroll
    for (int m = 0; m < 2; ++m) nA[m] = nid[r0 + m * 16 + l16];
    const _Float16* B = WaT + (t << 14);
    f32x4 acc[2][8];
#pragma unroll
    for (int m = 0; m < 2; ++m)
#pragma unroll
        for (int c = 0; c < 8; ++c) acc[m][c] = (f32x4){0.f, 0.f, 0.f, 0.f};
    for (int kk = 0; kk < 4; ++kk) {
        int kb = kk * 32 + quad * 8;
        half8 a[2];
#pragma unroll
        for (int m = 0; m < 2; ++m)
            a[m] = (nA[m] >= 0)
                       ? *(const half8*)(aggF + (size_t)nA[m] * DIM + kb)
                       : (half8){0, 0, 0, 0, 0, 0, 0, 0};
#pragma unroll
        for (int c = 0; c < 8; ++c) {
            half8 b = *(const half8*)(B + (c * 16 + l16) * DIM + kb);
#pragma unroll
            for (int m = 0; m < 2; ++m)
                acc[m][c] = __builtin_amdgcn_mfma_f32_16x16x32_f16(
                    a[m], b, acc[m][c], 0, 0, 0);
        }
    }
#pragma unroll
    for (int m = 0; m < 2; ++m)
#pragma unroll
        for (int c = 0; c < 8; ++c)
#pragma unroll
            for (int rg = 0; rg < 4; ++rg) {
                int node = nid[r0 + m * 16 + quad * 4 + rg];
                if (node >= 0)
                    out[(size_t)node * DIM + c * 16 + l16] =
                        acc[m][c][rg] * sig;
            }
}

extern "C" void kernel_launch(void* const* d_in, const int* in_sizes, int n_in,
                              void* d_out, int out_size, void* d_ws,
                              size_t ws_size, hipStream_t stream) {
    const float* h = (const float*)d_in[0];
    const int* adj = (const int*)d_in[1];
    const int* etype = (const int*)d_in[2];
    const int* ntype = (const int*)d_in[3];
    const float* Wk = (const float*)d_in[6];
    const float* Wq = (const float*)d_in[7];
    const float* Wv = (const float*)d_in[8];
    const float* Wa = (const float*)d_in[9];
    const float* pri = (const float*)d_in[10];
    const float* att = (const float*)d_in[11];
    const float* msg = (const float*)d_in[12];
    const float* skip = (const float*)d_in[13];
    float* out = (float*)d_out;

    int* wsi = (int*)d_ws + OFF_INT;
    _Float16* wsh = (_Float16*)d_ws;
    _Float16* UF = wsh + (size_t)OFF_U * 2;
    _Float16* hF = wsh + (size_t)OFF_HF * 2;
    _Float16* VMF = wsh + (size_t)OFF_VM * 2;
    _Float16* qF = wsh + (size_t)OFF_QF * 2;
    _Float16* kF = wsh + (size_t)OFF_KF * 2;
    _Float16* aggF = wsh + (size_t)OFF_AGGF * 2;
    _Float16* vF = wsh + (size_t)OFF_VF * 2;
    _Float16* attF = wsh + (size_t)OFF_ATTF * 2;
    _Float16* msgT = wsh + (size_t)OFF_MSGT * 2;
    _Float16* WvT = wsh + (size_t)OFF_WVT * 2;
    _Float16* WaT = wsh + (size_t)OFF_WAT * 2;

    init_kernel<<<(100000 + 255) / 256, 256, 0, stream>>>(wsi);
    convert_kernel<<<(RR * DIM * DIM + 255) / 256, 256, 0, stream>>>(
        att, msg, Wv, Wa, attF, msgT, WvT, WaT);
    hconv_kernel<<<(N_NODES * DIM / 4 + 255) / 256, 256, 0, stream>>>(h, hF);
    hist_kernel<<<GRID_E, 256, 0, stream>>>(ntype, adj, wsi);
    offsets_kernel<<<1, 1, 0, stream>>>(wsi);
    dst_scan_kernel<<<1, 256, 0, stream>>>(wsi);
    scatter_kernel<<<GRID_E, 256, 0, stream>>>(ntype, etype, adj, wsi);
    kq_f32_kernel<<<CHUNK_GRID * 4, 256, 0, stream>>>(h, ntype, Wk, Wq,
                                                      wsi + IO_NLIST, kF, qF);
    vproj_kernel<<<CHUNK_GRID, 256, 0, stream>>>(hF, ntype, WvT,
                                                 wsi + IO_NLIST, vF);
    {
        dim3 g(GEMM_ROWBLKS, RR);
        nr_gemm_kernel<<<g, 256, 0, stream>>>(qF, attF, UF, pri, 1);
        nr_gemm_kernel<<<g, 256, 0, stream>>>(vF, msgT, VMF, pri, 0);
    }
    attend_kernel<<<(N_NODES + 3) / 4, 256, 0, stream>>>(
        kF, UF, VMF, wsi + IO_DPR, wsi + IO_DOFF, wsi + IO_DCNT, aggF);
    out_kernel<<<CHUNK_GRID, 256, 0, stream>>>(aggF, ntype, WaT, skip,
                                               wsi + IO_NLIST, out);
}

// Round 10
// 473.384 us; speedup vs baseline: 12.0628x; 1.1966x over previous
//
#include <hip/hip_runtime.h>
#include <math.h>

// ---------------------------------------------------------------------------
// HGT layer slice. R10: parallel dst scan (R9 post-mortem: single-block
// 50k-element scan = 105 us at 0.04% occupancy -> hierarchical 3-phase scan).
//
// attend v2.1 (R9-proven): 16 lanes/edge, 4 edges in flight; lane-owned
// softmax state; wave-uniform parking; padding edges masked (ex=0).
// Score path fp32 (R6 post-mortem), value path f16 MFMA.
//
// Pipeline: init -> convert -> hconv -> hist -> offsets -> scanA/B/C ->
// scatter -> kq_f32 -> vproj(MFMA) -> U gemm(pri*rsqrt_dk folded) ->
// VM gemm -> attend -> out(MFMA).
// ---------------------------------------------------------------------------

#define N_NODES 50000
#define N_EDGES 500000
#define DIM 128
#define TT 8
#define RR 8
#define RSQRT_DK 0.08838834764831845f

#define CHUNK_GRID 399               // 399*128 = 51072 >= 50000 + 8*127
#define NODE_LIST_LEN (CHUNK_GRID * 128)
#define GRID_E ((N_EDGES + 255) / 256)   // 1954, also covers N
#define GEMM_ROWBLKS ((N_NODES + 127) / 128)  // 391
#define SCAN_BLOCKS ((N_NODES + 255) / 256)   // 196

// word offsets (4B units); _Float16 index = 2*word
#define OFF_U 0
#define OFF_HF 0                   // alias: hF16 [n][128] (dead before U write)
#define OFF_VM 25600000
#define OFF_QF 25600000            // alias: qF16 (dead before VM write)
#define OFF_KF 51200000
#define OFF_AGGF 54400000
#define OFF_VF 54400000            // alias: vF16 (dead before attend writes agg)
#define OFF_ATTF 57600000          // 65,536 words each, 100k spacing
#define OFF_MSGT 57700000
#define OFF_WVT 57800000
#define OFF_WAT 57900000
#define OFF_INT 58000000           // int region, +701,872 -> 58,701,872 words
#define IO_NLIST 0                 // 51,072
#define IO_CNT_N 51072
#define IO_CUR_N 51080
#define IO_POFF_N 51088
#define IO_DCNT 51104              // 50,000
#define IO_DCUR 101104             // 50,000
#define IO_DOFF 151104             // 50,000
#define IO_DPR 201104              // 500,000 packed (src*8|rel) per CSR slot
#define IO_BLKSUM 701104           // 256 per-scan-block totals
#define IO_BLKOFF 701360           // 256 scanned block offsets; end 701,616

typedef _Float16 half8 __attribute__((ext_vector_type(8)));
typedef _Float16 half4 __attribute__((ext_vector_type(4)));
typedef float f32x4 __attribute__((ext_vector_type(4)));

__global__ void init_kernel(int* wsi) {
    int i = blockIdx.x * blockDim.x + threadIdx.x;
    if (i < NODE_LIST_LEN) wsi[IO_NLIST + i] = -1;
    if (i < 32) wsi[IO_CNT_N + i] = 0;
    if (i < 100000) wsi[IO_DCNT + i] = 0;  // dcnt + dcur contiguous
}

// attF straight [r][d][f]; msgT/WvT/WaT transposed to [.][f][d], all f16
__global__ void convert_kernel(const float* __restrict__ att,
                               const float* __restrict__ msg,
                               const float* __restrict__ Wv,
                               const float* __restrict__ Wa,
                               _Float16* __restrict__ attF,
                               _Float16* __restrict__ msgT,
                               _Float16* __restrict__ WvT,
                               _Float16* __restrict__ WaT) {
    int i = blockIdx.x * 256 + threadIdx.x;
    if (i >= RR * DIM * DIM) return;
    int td = i >> 14, d = (i >> 7) & 127, f = i & 127;
    int tr = (td << 14) + (f << 7) + d;
    attF[i] = (_Float16)att[i];
    msgT[tr] = (_Float16)msg[i];
    WvT[tr] = (_Float16)Wv[i];
    WaT[tr] = (_Float16)Wa[i];
}

__global__ void hconv_kernel(const float* __restrict__ h,
                             _Float16* __restrict__ hF) {
    int i = blockIdx.x * 256 + threadIdx.x;
    if (i < N_NODES * DIM / 4) {
        float4 v = ((const float4*)h)[i];
        half4 o;
        o[0] = (_Float16)v.x; o[1] = (_Float16)v.y;
        o[2] = (_Float16)v.z; o[3] = (_Float16)v.w;
        *(half4*)(hF + (size_t)i * 4) = o;
    }
}

__global__ void hist_kernel(const int* __restrict__ ntype,
                            const int* __restrict__ adj, int* wsi) {
    __shared__ int cn[TT];
    int tid = threadIdx.x;
    if (tid < TT) cn[tid] = 0;
    __syncthreads();
    int i = blockIdx.x * blockDim.x + tid;
    if (i < N_NODES) atomicAdd(&cn[ntype[i]], 1);
    if (i < N_EDGES) atomicAdd(&wsi[IO_DCNT + adj[N_EDGES + i]], 1);
    __syncthreads();
    if (tid < TT && cn[tid] > 0) atomicAdd(&wsi[IO_CNT_N + tid], cn[tid]);
}

__global__ void offsets_kernel(int* wsi) {
    int off = 0;
    for (int t = 0; t < TT; ++t) {
        wsi[IO_POFF_N + t] = off;
        off += ((wsi[IO_CNT_N + t] + 127) >> 7) << 7;  // pad to 128
    }
}

// 3-phase parallel exclusive scan of the 50k dst counts (R9: 1-block = 105us)
__global__ __launch_bounds__(256) void scanA_kernel(int* wsi) {
    __shared__ int tmp[256];
    int tid = threadIdx.x;
    int i = blockIdx.x * 256 + tid;
    int v = (i < N_NODES) ? wsi[IO_DCNT + i] : 0;
    tmp[tid] = v;
    __syncthreads();
    for (int off = 1; off < 256; off <<= 1) {
        int t = (tid >= off) ? tmp[tid - off] : 0;
        __syncthreads();
        tmp[tid] += t;
        __syncthreads();
    }
    if (i < N_NODES) wsi[IO_DOFF + i] = tmp[tid] - v;  // block-local exclusive
    if (tid == 255) wsi[IO_BLKSUM + blockIdx.x] = tmp[255];
}

__global__ __launch_bounds__(256) void scanB_kernel(int* wsi) {
    __shared__ int tmp[256];
    int tid = threadIdx.x;
    int v = (tid < SCAN_BLOCKS) ? wsi[IO_BLKSUM + tid] : 0;
    tmp[tid] = v;
    __syncthreads();
    for (int off = 1; off < 256; off <<= 1) {
        int t = (tid >= off) ? tmp[tid - off] : 0;
        __syncthreads();
        tmp[tid] += t;
        __syncthreads();
    }
    wsi[IO_BLKOFF + tid] = tmp[tid] - v;
}

__global__ __launch_bounds__(256) void scanC_kernel(int* wsi) {
    int i = blockIdx.x * 256 + threadIdx.x;
    if (i < N_NODES) wsi[IO_DOFF + i] += wsi[IO_BLKOFF + blockIdx.x];
}

__global__ void scatter_kernel(const int* __restrict__ ntype,
                               const int* __restrict__ etype,
                               const int* __restrict__ adj, int* wsi) {
    __shared__ int cn[TT], bn[TT];
    int tid = threadIdx.x;
    if (tid < TT) cn[tid] = 0;
    __syncthreads();
    int i = blockIdx.x * blockDim.x + tid;
    int t = -1, rnk = 0;
    if (i < N_NODES) {
        t = ntype[i];
        rnk = atomicAdd(&cn[t], 1);
    }
    __syncthreads();
    if (tid < TT && cn[tid] > 0) bn[tid] = atomicAdd(&wsi[IO_CUR_N + tid], cn[tid]);
    __syncthreads();
    if (t >= 0)
        wsi[IO_NLIST + wsi[IO_POFF_N + t] + bn[t] + rnk] = i;
    if (i < N_EDGES) {
        int d = adj[N_EDGES + i];
        int pos = wsi[IO_DOFF + d] + atomicAdd(&wsi[IO_DCUR + d], 1);
        wsi[IO_DPR + pos] = (adj[i] << 3) | etype[i];  // packed src*8|rel
    }
}

// k,q: fp32 vector tile GEMM (score path is argmax-sensitive; R6 post-mortem)
__global__ __launch_bounds__(256) void kq_f32_kernel(
    const float* __restrict__ h, const int* __restrict__ ntype,
    const float* __restrict__ Wk, const float* __restrict__ Wq,
    const int* __restrict__ nlist, _Float16* __restrict__ kout,
    _Float16* __restrict__ qout) {
    __shared__ float hl[32][DIM + 4];
    __shared__ int nid[32];
    int tid = threadIdx.x;
    int base = blockIdx.x * 32;
    if (tid < 32) nid[tid] = nlist[base + tid];
    __syncthreads();
    if (nid[0] < 0) return;
    int t = ntype[nid[0]];

    for (int r2 = 0; r2 < 32; r2 += 2) {
        int row = r2 + (tid >> 7);
        int col = tid & 127;
        int n = nid[row];
        if (n < 0) n = 0;
        hl[row][col] = h[(size_t)n * DIM + col];
    }
    __syncthreads();
    int te = tid >> 5, tc = tid & 31;

#pragma unroll
    for (int w = 0; w < 2; ++w) {
        const float* W = (w == 0 ? Wk : Wq) + (size_t)t * DIM * DIM;
        const float4* W4 = (const float4*)W;
        _Float16* O = (w == 0 ? kout : qout);
        float acc[4][4] = {};
        for (int i = 0; i < DIM; ++i) {
            float4 a = W4[i * 32 + tc];
#pragma unroll
            for (int j = 0; j < 4; ++j) {
                float hv = hl[te * 4 + j][i];
                acc[j][0] += hv * a.x;
                acc[j][1] += hv * a.y;
                acc[j][2] += hv * a.z;
                acc[j][3] += hv * a.w;
            }
        }
#pragma unroll
        for (int j = 0; j < 4; ++j) {
            int n = nid[te * 4 + j];
            if (n >= 0) {
                half4 o;
                o[0] = (_Float16)acc[j][0];
                o[1] = (_Float16)acc[j][1];
                o[2] = (_Float16)acc[j][2];
                o[3] = (_Float16)acc[j][3];
                *(half4*)(O + (size_t)n * DIM + tc * 4) = o;
            }
        }
    }
}

// v: 128-node type-uniform chunk MFMA GEMM (value path: f16-tolerant)
__global__ __launch_bounds__(256) void vproj_kernel(
    const _Float16* __restrict__ hF, const int* __restrict__ ntype,
    const _Float16* __restrict__ WvT, const int* __restrict__ nlist,
    _Float16* __restrict__ vout) {
    __shared__ int nid[128];
    int tid = threadIdx.x;
    if (tid < 128) nid[tid] = nlist[blockIdx.x * 128 + tid];
    __syncthreads();
    if (nid[0] < 0) return;
    int t = ntype[nid[0]];
    int wv = tid >> 6, lane = tid & 63, l16 = lane & 15, quad = lane >> 4;
    int r0 = wv * 32;
    int nA[2];
#pragma unroll
    for (int m = 0; m < 2; ++m) nA[m] = nid[r0 + m * 16 + l16];
    const _Float16* B = WvT + (t << 14);
    f32x4 acc[2][8];
#pragma unroll
    for (int m = 0; m < 2; ++m)
#pragma unroll
        for (int c = 0; c < 8; ++c) acc[m][c] = (f32x4){0.f, 0.f, 0.f, 0.f};
    for (int kk = 0; kk < 4; ++kk) {
        int kb = kk * 32 + quad * 8;
        half8 a[2];
#pragma unroll
        for (int m = 0; m < 2; ++m)
            a[m] = (nA[m] >= 0)
                       ? *(const half8*)(hF + (size_t)nA[m] * DIM + kb)
                       : (half8){0, 0, 0, 0, 0, 0, 0, 0};
#pragma unroll
        for (int c = 0; c < 8; ++c) {
            half8 b = *(const half8*)(B + (c * 16 + l16) * DIM + kb);
#pragma unroll
            for (int m = 0; m < 2; ++m)
                acc[m][c] = __builtin_amdgcn_mfma_f32_16x16x32_f16(
                    a[m], b, acc[m][c], 0, 0, 0);
        }
    }
#pragma unroll
    for (int m = 0; m < 2; ++m)
#pragma unroll
        for (int c = 0; c < 8; ++c)
#pragma unroll
            for (int rg = 0; rg < 4; ++rg) {
                int node = nid[r0 + m * 16 + quad * 4 + rg];
                if (node >= 0)
                    vout[(size_t)node * DIM + c * 16 + l16] =
                        (_Float16)acc[m][c][rg];
            }
}

// Dense MFMA GEMM: Out[n, rel, col] = scale_r * sum_k A[n,k] * B[rel, col, k]
__global__ __launch_bounds__(256) void nr_gemm_kernel(
    const _Float16* __restrict__ A, const _Float16* __restrict__ B,
    _Float16* __restrict__ Of, const float* __restrict__ pri, int doscale) {
    int rel = blockIdx.y;
    int tid = threadIdx.x;
    int wv = tid >> 6, lane = tid & 63;
    int l16 = lane & 15, quad = lane >> 4;
    int row0 = blockIdx.x * 128 + wv * 32;
    const _Float16* Bbase = B + rel * DIM * DIM;
    float scale = doscale ? pri[rel] * RSQRT_DK : 1.0f;
    f32x4 acc[2][8];
#pragma unroll
    for (int m = 0; m < 2; ++m)
#pragma unroll
        for (int c = 0; c < 8; ++c) acc[m][c] = (f32x4){0.f, 0.f, 0.f, 0.f};

    for (int kk = 0; kk < 4; ++kk) {
        int kb = kk * 32 + quad * 8;
        half8 a[2];
#pragma unroll
        for (int m = 0; m < 2; ++m) {
            int node = row0 + m * 16 + l16;
            if (node < N_NODES)
                a[m] = *(const half8*)(A + (size_t)node * DIM + kb);
            else
                a[m] = (half8){0, 0, 0, 0, 0, 0, 0, 0};
        }
#pragma unroll
        for (int c = 0; c < 8; ++c) {
            half8 b = *(const half8*)(Bbase + (c * 16 + l16) * DIM + kb);
#pragma unroll
            for (int m = 0; m < 2; ++m)
                acc[m][c] = __builtin_amdgcn_mfma_f32_16x16x32_f16(
                    a[m], b, acc[m][c], 0, 0, 0);
        }
    }
#pragma unroll
    for (int m = 0; m < 2; ++m)
#pragma unroll
        for (int c = 0; c < 8; ++c)
#pragma unroll
            for (int rg = 0; rg < 4; ++rg) {
                int node = row0 + m * 16 + quad * 4 + rg;
                if (node < N_NODES)
                    Of[((size_t)node * RR + rel) * DIM + c * 16 + l16] =
                        (_Float16)(acc[m][c][rg] * scale);
            }
}

// ---------------------------------------------------------------------------
// attend v2.1 (R9-proven): fused score+softmax+aggregate, one wave per dst.
// ---------------------------------------------------------------------------
__global__ __launch_bounds__(256) void attend_kernel(
    const _Float16* __restrict__ kF, const _Float16* __restrict__ UF,
    const _Float16* __restrict__ VMF, const int* __restrict__ dpr,
    const int* __restrict__ doff, const int* __restrict__ dcnt,
    _Float16* __restrict__ aggF) {
    int wv = threadIdx.x >> 6, lane = threadIdx.x & 63;
    int dst = blockIdx.x * 4 + wv;
    if (dst >= N_NODES) return;
    int l16 = lane & 15, g = lane >> 4, l8 = lane & 7;
    int beg = doff[dst], cnt = dcnt[dst];

    float m_own = -3e38f, sum_own = 0.f;
    float s0 = 0.f, s1 = 0.f, s2 = 0.f;
    int p0 = 0, p1 = 0, p2 = 0;

    // phase 1: scores, park (s, pr), lane-owned per-rel max
    for (int j0 = 0; j0 < cnt; j0 += 4) {
        int j = j0 + g;
        bool valid = j < cnt;
        int pr = valid ? dpr[beg + j] : 0;
        int src = pr >> 3, rel = pr & 7;
        half8 kv = *(const half8*)(kF + (size_t)src * DIM + l16 * 8);
        half8 uv =
            *(const half8*)(UF + ((size_t)dst * RR + rel) * DIM + l16 * 8);
        float s = 0.f;
#pragma unroll
        for (int i = 0; i < 8; ++i) s += (float)kv[i] * (float)uv[i];
        s += __shfl_xor(s, 1, 16);
        s += __shfl_xor(s, 2, 16);
        s += __shfl_xor(s, 4, 16);
        s += __shfl_xor(s, 8, 16);
        if (!valid) s = -3e38f;
        int slot = j0 >> 6;            // wave-uniform
        int idx = (j0 >> 2) & 15;      // wave-uniform
        if (l16 == idx) {
            if (slot == 0) { s0 = s; p0 = pr; }
            else if (slot == 1) { s1 = s; p1 = pr; }
            else if (slot == 2) { s2 = s; p2 = pr; }
        }
        if (valid && l8 == rel && s > m_own) m_own = s;
    }
    // merge per-rel max across the 4 groups
    m_own = fmaxf(m_own, __shfl_xor(m_own, 16, 64));
    m_own = fmaxf(m_own, __shfl_xor(m_own, 32, 64));

    // phase 2: ex = valid ? exp(s - m[rel]) : 0; park ex; lane-owned sum
    for (int j0 = 0; j0 < cnt; j0 += 4) {
        int j = j0 + g;
        bool valid = j < cnt;
        int slot = j0 >> 6;
        int idx = (j0 >> 2) & 15;
        float s;
        int pr;
        if (slot < 3) {
            float sv = (slot == 0) ? s0 : (slot == 1) ? s1 : s2;
            int pv = (slot == 0) ? p0 : (slot == 1) ? p1 : p2;
            s = __shfl(sv, idx, 16);
            pr = __shfl(pv, idx, 16);
        } else {  // overflow fallback: recompute (cnt>192 ~ never at deg~10)
            pr = valid ? dpr[beg + j] : 0;
            int src = pr >> 3, rel = pr & 7;
            half8 kv = *(const half8*)(kF + (size_t)src * DIM + l16 * 8);
            half8 uv =
                *(const half8*)(UF + ((size_t)dst * RR + rel) * DIM + l16 * 8);
            s = 0.f;
#pragma unroll
            for (int i = 0; i < 8; ++i) s += (float)kv[i] * (float)uv[i];
            s += __shfl_xor(s, 1, 16);
            s += __shfl_xor(s, 2, 16);
            s += __shfl_xor(s, 4, 16);
            s += __shfl_xor(s, 8, 16);
        }
        int rel = pr & 7;
        float mr = __shfl(m_own, rel, 8);
        float ex = valid ? __expf(s - mr) : 0.f;  // mask padding edges
        if (l16 == idx) {
            if (slot == 0) s0 = ex;
            else if (slot == 1) s1 = ex;
            else if (slot == 2) s2 = ex;
        }
        if (l8 == rel) sum_own += ex;
    }
    // merge per-rel sums; invert once
    sum_own += __shfl_xor(sum_own, 16, 64);
    sum_own += __shfl_xor(sum_own, 32, 64);
    float inv_own = (sum_own > 0.f) ? 1.f / sum_own : 0.f;

    // phase 3: acc += alpha * VM[src, rel]  (parked ex is already 0 for pads)
    float acc[8] = {0.f, 0.f, 0.f, 0.f, 0.f, 0.f, 0.f, 0.f};
    for (int j0 = 0; j0 < cnt; j0 += 4) {
        int j = j0 + g;
        bool valid = j < cnt;
        int slot = j0 >> 6;
        int idx = (j0 >> 2) & 15;
        float ex;
        int pr;
        if (slot < 3) {
            float sv = (slot == 0) ? s0 : (slot == 1) ? s1 : s2;
            int pv = (slot == 0) ? p0 : (slot == 1) ? p1 : p2;
            ex = __shfl(sv, idx, 16);
            pr = __shfl(pv, idx, 16);
        } else {
            pr = valid ? dpr[beg + j] : 0;
            int src = pr >> 3, rel = pr & 7;
            half8 kv = *(const half8*)(kF + (size_t)src * DIM + l16 * 8);
            half8 uv =
                *(const half8*)(UF + ((size_t)dst * RR + rel) * DIM + l16 * 8);
            float s = 0.f;
#pragma unroll
            for (int i = 0; i < 8; ++i) s += (float)kv[i] * (float)uv[i];
            s += __shfl_xor(s, 1, 16);
            s += __shfl_xor(s, 2, 16);
            s += __shfl_xor(s, 4, 16);
            s += __shfl_xor(s, 8, 16);
            float mr = __shfl(m_own, (pr & 7), 8);
            ex = valid ? __expf(s - mr) : 0.f;
        }
        int rel = pr & 7, src = pr >> 3;
        float alpha = ex * __shfl(inv_own, rel, 8);
        half8 v =
            *(const half8*)(VMF + ((size_t)src * RR + rel) * DIM + l16 * 8);
#pragma unroll
        for (int i = 0; i < 8; ++i) acc[i] += alpha * (float)v[i];
    }
    // merge acc across the 4 groups (each covers the full 128 dims)
#pragma unroll
    for (int i = 0; i < 8; ++i) {
        acc[i] += __shfl_xor(acc[i], 16, 64);
        acc[i] += __shfl_xor(acc[i], 32, 64);
    }
    if (g == 0) {
        half8 o;
#pragma unroll
        for (int i = 0; i < 8; ++i) o[i] = (_Float16)acc[i];
        *(half8*)(aggF + (size_t)dst * DIM + l16 * 8) = o;
    }
}

// out: 128-node type-uniform chunk MFMA GEMM, fp32 stores with sigmoid gate
__global__ __launch_bounds__(256) void out_kernel(
    const _Float16* __restrict__ aggF, const int* __restrict__ ntype,
    const _Float16* __restrict__ WaT, const float* __restrict__ skip,
    const int* __restrict__ nlist, float* __restrict__ out) {
    __shared__ int nid[128];
    int tid = threadIdx.x;
    if (tid < 128) nid[tid] = nlist[blockIdx.x * 128 + tid];
    __syncthreads();
    if (nid[0] < 0) return;
    int t = ntype[nid[0]];
    float sig = 1.f / (1.f + __expf(-skip[t]));
    int wv = tid >> 6, lane = tid & 63, l16 = lane & 15, quad = lane >> 4;
    int r0 = wv * 32;
    int nA[2];
#pragma unroll
    for (int m = 0; m < 2; ++m) nA[m] = nid[r0 + m * 16 + l16];
    const _Float16* B = WaT + (t << 14);
    f32x4 acc[2][8];
#pragma unroll
    for (int m = 0; m < 2; ++m)
#pragma unroll
        for (int c = 0; c < 8; ++c) acc[m][c] = (f32x4){0.f, 0.f, 0.f, 0.f};
    for (int kk = 0; kk < 4; ++kk) {
        int kb = kk * 32 + quad * 8;
        half8 a[2];
#pragma unroll
        for (int m = 0; m < 2; ++m)
            a[m] = (nA[m] >= 0)
                       ? *(const half8*)(aggF + (size_t)nA[m] * DIM + kb)
                       : (half8){0, 0, 0, 0, 0, 0, 0, 0};
#pragma unroll
        for (int c = 0; c < 8; ++c) {
            half8 b = *(const half8*)(B + (c * 16 + l16) * DIM + kb);
#pragma unroll
            for (int m = 0; m < 2; ++m)
                acc[m][c] = __builtin_amdgcn_mfma_f32_16x16x32_f16(
                    a[m], b, acc[m][c], 0, 0, 0);
        }
    }
#pragma unroll
    for (int m = 0; m < 2; ++m)
#pragma unroll
        for (int c = 0; c < 8; ++c)
#pragma unroll
            for (int rg = 0; rg < 4; ++rg) {
                int node = nid[r0 + m * 16 + quad * 4 + rg];
                if (node >= 0)
                    out[(size_t)node * DIM + c * 16 + l16] =
                        acc[m][c][rg] * sig;
            }
}

extern "C" void kernel_launch(void* const* d_in, const int* in_sizes, int n_in,
                              void* d_out, int out_size, void* d_ws,
                              size_t ws_size, hipStream_t stream) {
    const float* h = (const float*)d_in[0];
    const int* adj = (const int*)d_in[1];
    const int* etype = (const int*)d_in[2];
    const int* ntype = (const int*)d_in[3];
    const float* Wk = (const float*)d_in[6];
    const float* Wq = (const float*)d_in[7];
    const float* Wv = (const float*)d_in[8];
    const float* Wa = (const float*)d_in[9];
    const float* pri = (const float*)d_in[10];
    const float* att = (const float*)d_in[11];
    const float* msg = (const float*)d_in[12];
    const float* skip = (const float*)d_in[13];
    float* out = (float*)d_out;

    int* wsi = (int*)d_ws + OFF_INT;
    _Float16* wsh = (_Float16*)d_ws;
    _Float16* UF = wsh + (size_t)OFF_U * 2;
    _Float16* hF = wsh + (size_t)OFF_HF * 2;
    _Float16* VMF = wsh + (size_t)OFF_VM * 2;
    _Float16* qF = wsh + (size_t)OFF_QF * 2;
    _Float16* kF = wsh + (size_t)OFF_KF * 2;
    _Float16* aggF = wsh + (size_t)OFF_AGGF * 2;
    _Float16* vF = wsh + (size_t)OFF_VF * 2;
    _Float16* attF = wsh + (size_t)OFF_ATTF * 2;
    _Float16* msgT = wsh + (size_t)OFF_MSGT * 2;
    _Float16* WvT = wsh + (size_t)OFF_WVT * 2;
    _Float16* WaT = wsh + (size_t)OFF_WAT * 2;

    init_kernel<<<(100000 + 255) / 256, 256, 0, stream>>>(wsi);
    convert_kernel<<<(RR * DIM * DIM + 255) / 256, 256, 0, stream>>>(
        att, msg, Wv, Wa, attF, msgT, WvT, WaT);
    hconv_kernel<<<(N_NODES * DIM / 4 + 255) / 256, 256, 0, stream>>>(h, hF);
    hist_kernel<<<GRID_E, 256, 0, stream>>>(ntype, adj, wsi);
    offsets_kernel<<<1, 1, 0, stream>>>(wsi);
    scanA_kernel<<<SCAN_BLOCKS, 256, 0, stream>>>(wsi);
    scanB_kernel<<<1, 256, 0, stream>>>(wsi);
    scanC_kernel<<<SCAN_BLOCKS, 256, 0, stream>>>(wsi);
    scatter_kernel<<<GRID_E, 256, 0, stream>>>(ntype, etype, adj, wsi);
    kq_f32_kernel<<<CHUNK_GRID * 4, 256, 0, stream>>>(h, ntype, Wk, Wq,
                                                      wsi + IO_NLIST, kF, qF);
    vproj_kernel<<<CHUNK_GRID, 256, 0, stream>>>(hF, ntype, WvT,
                                                 wsi + IO_NLIST, vF);
    {
        dim3 g(GEMM_ROWBLKS, RR);
        nr_gemm_kernel<<<g, 256, 0, stream>>>(qF, attF, UF, pri, 1);
        nr_gemm_kernel<<<g, 256, 0, stream>>>(vF, msgT, VMF, pri, 0);
    }
    attend_kernel<<<(N_NODES + 3) / 4, 256, 0, stream>>>(
        kF, UF, VMF, wsi + IO_DPR, wsi + IO_DOFF, wsi + IO_DCNT, aggF);
    out_kernel<<<CHUNK_GRID, 256, 0, stream>>>(aggF, ntype, WaT, skip,
                                               wsi + IO_NLIST, out);
}